// Round 12
// baseline (974.495 us; speedup 1.0000x reference)
//
#include <hip/hip_runtime.h>
#include <hip/hip_bf16.h>
#include <math.h>

#define NE 8000
#define NN 1000
#define CAP 64
#define PLANE 256000   // 8000*32

typedef unsigned short ushortt;
typedef __attribute__((ext_vector_type(8))) short short8;
typedef __attribute__((ext_vector_type(4))) float f32x4;

// ---------------- CG tables metadata ----------------
__device__ const int KEYL[11][3] = {{0,0,0},{0,1,1},{0,2,2},{1,0,1},{1,1,0},{1,1,2},{1,2,1},{2,0,2},{2,1,1},{2,2,0},{2,2,2}};
__device__ const int KEYOFF[12] = {0,1,10,35,44,53,98,143,168,213,238,363};

struct PathT { int li, ls, lo, cgoff, comp; };
__device__ const PathT PATHS[11] = {
 {0,0,0,  0, 0},{0,1,1,  1, 1},{0,2,2, 10, 4},{1,0,1, 35, 9},{1,1,0, 44,12},{1,1,2, 53,13},
 {1,2,1, 98,18},{2,0,2,143,21},{2,1,1,168,26},{2,2,0,213,29},{2,2,2,238,30}};

// ---- compile-time tables for the product kernel ----
struct CPair { int l1,l2,cga; };
struct CTrip { int l1,l2,L,cga,l3,cgb; };
constexpr CPair cPR0[3]={{0,0,0},{1,1,44},{2,2,213}};
constexpr CPair cPR1[4]={{0,1,1},{1,0,35},{1,2,98},{2,1,168}};
constexpr CPair cPR2[4]={{0,2,10},{1,1,53},{2,0,143},{2,2,238}};
constexpr CTrip cTR0[11]={
  {0,0,0,0,0,0},{1,1,0,44,0,0},{2,2,0,213,0,0},
  {0,1,1,1,1,44},{1,0,1,35,1,44},{1,2,1,98,1,44},{2,1,1,168,1,44},
  {0,2,2,10,2,213},{1,1,2,53,2,213},{2,0,2,143,2,213},{2,2,2,238,2,213}};
constexpr CTrip cTR1[15]={
  {0,0,0,0,1,1},{1,1,0,44,1,1},{2,2,0,213,1,1},
  {0,1,1,1,0,35},{1,0,1,35,0,35},{1,2,1,98,0,35},{2,1,1,168,0,35},
  {0,1,1,1,2,98},{1,0,1,35,2,98},{1,2,1,98,2,98},{2,1,1,168,2,98},
  {0,2,2,10,1,168},{1,1,2,53,1,168},{2,0,2,143,1,168},{2,2,2,238,1,168}};
constexpr CTrip cTR2[15]={
  {0,0,0,0,2,10},{1,1,0,44,2,10},{2,2,0,213,2,10},
  {0,1,1,1,1,53},{1,0,1,35,1,53},{1,2,1,98,1,53},{2,1,1,168,1,53},
  {0,2,2,10,0,143},{1,1,2,53,0,143},{2,0,2,143,0,143},{2,2,2,238,0,143},
  {0,2,2,10,2,238},{1,1,2,53,2,238},{2,0,2,143,2,238},{2,2,2,238,2,238}};
constexpr CPair getPR(int lo,int p){ return lo==0?cPR0[p]:(lo==1?cPR1[p]:cPR2[p]); }
constexpr CTrip getTR(int lo,int p){ return lo==0?cTR0[p]:(lo==1?cTR1[p]:cTR2[p]); }
constexpr int cloff(int l){ return l==0?0:(l==1?1:4); }
constexpr int nPR(int lo){ return lo==0?3:4; }
constexpr int nTR(int lo){ return lo==0?11:15; }

template<int I> struct ic_t { static constexpr int v = I; };
template<int N, int I=0, typename F>
__device__ __forceinline__ void sfor(F&& f){
  if constexpr (I < N){ f(ic_t<I>{}); sfor<N, I+1>((F&&)f); }
}

__device__ __forceinline__ int loff_(int l){ return l==0?0:(l==1?1:4); }

__device__ __forceinline__ ushortt f2bf(float x){
  union { float f; unsigned int u; } a; a.f = x;
  unsigned int r = a.u + 0x7FFFu + ((a.u >> 16) & 1u);
  return (ushortt)(r >> 16);
}

// ---------------- device CG math ----------------
__device__ double d_fact(int n){ double f=1.0; for(int i=2;i<=n;i++) f*=(double)i; return f; }

__device__ double d_cg(int j1,int m1,int j2,int m2,int J,int M){
  if (M != m1+m2 || J < abs(j1-j2) || J > j1+j2) return 0.0;
  double pre = sqrt((2.0*J+1.0)*d_fact(J+j1-j2)*d_fact(J-j1+j2)*d_fact(j1+j2-J)/d_fact(j1+j2+J+1));
  pre *= sqrt(d_fact(J+M)*d_fact(J-M)*d_fact(j1-m1)*d_fact(j1+m1)*d_fact(j2-m2)*d_fact(j2+m2));
  double s=0.0;
  for(int k=0;k<=j1+j2-J;k++){
    int d0=k, d1=j1+j2-J-k, d2=j1-m1-k, d3=j2+m2-k, d4=J-j2+m1+k, d5=J-j1-m2+k;
    if (d0<0||d1<0||d2<0||d3<0||d4<0||d5<0) continue;
    double den = d_fact(d0)*d_fact(d1)*d_fact(d2)*d_fact(d3)*d_fact(d4)*d_fact(d5);
    s += ((k&1)?-1.0:1.0)/den;
  }
  return pre*s;
}

__device__ void d_u(int l, int i, int j, double* re, double* im){
  int m = i - l;
  *re=0.0; *im=0.0;
  const double s2 = 0.70710678118654752440;
  double par = (m & 1) ? -1.0 : 1.0;
  if (m < 0){
    if (j == m + l)  *im += s2;
    if (j == -m + l) *im += -par*s2;
  } else if (m == 0){
    if (j == l) *re = 1.0;
  } else {
    if (j == -m + l) *re += s2;
    if (j == m + l)  *re += par*s2;
  }
}

__global__ __launch_bounds__(128) void kcg1(double* tmp){
  int key = blockIdx.x;
  int l1=KEYL[key][0], l2=KEYL[key][1], l3=KEYL[key][2];
  int n1=2*l1+1, n2=2*l2+1, n3=2*l3+1;
  int nel=n1*n2*n3;
  int t=threadIdx.x;
  if (t>=nel) return;
  int a=t/(n2*n3), b=(t/n3)%n2, c=t%n3;
  double sre=0.0, sim=0.0;
  for (int mi=0;mi<n1;mi++)
    for (int ni=0;ni<n2;ni++){
      int m3 = (mi-l1)+(ni-l2);
      int oi = m3 + l3;
      if (oi<0 || oi>=n3) continue;
      double tc = d_cg(l1,mi-l1,l2,ni-l2,l3,m3);
      if (tc==0.0) continue;
      double r1,i1,r2,i2,r3,i3;
      d_u(l1,a,mi,&r1,&i1);
      d_u(l2,b,ni,&r2,&i2);
      d_u(l3,c,oi,&r3,&i3);
      double rr = r1*r2 - i1*i2;
      double ri = r1*i2 + i1*r2;
      double fr = rr*r3 + ri*i3;
      double fi = ri*r3 - rr*i3;
      sre += fr*tc; sim += fi*tc;
    }
  tmp[(size_t)(KEYOFF[key]+t)*2]   = sre;
  tmp[(size_t)(KEYOFF[key]+t)*2+1] = sim;
}

__global__ __launch_bounds__(64) void kcg2(const double* tmp, float* cgf){
  int key=threadIdx.x;
  if (key>=11) return;
  int off=KEYOFF[key], n=KEYOFF[key+1]-off;
  double sre=0.0, sim=0.0;
  for (int i=0;i<n;i++){ sre += fabs(tmp[(size_t)(off+i)*2]); sim += fabs(tmp[(size_t)(off+i)*2+1]); }
  bool takeRe = (sre >= sim);
  for (int i=0;i<n;i++) cgf[off+i] = (float)(takeRe ? tmp[(size_t)(off+i)*2] : tmp[(size_t)(off+i)*2+1]);
}

// ---------------- edge geometry ----------------
__global__ __launch_bounds__(256) void kgeom(const float* __restrict__ pos, const int* __restrict__ ei,
                                             float* __restrict__ shb, float* __restrict__ efb){
  int e = blockIdx.x*256+threadIdx.x;
  if (e>=NE) return;
  int s=ei[e], d=ei[NE+e];
  float vx=pos[s*3]-pos[d*3], vy=pos[s*3+1]-pos[d*3+1], vz=pos[s*3+2]-pos[d*3+2];
  float r = sqrtf(vx*vx+vy*vy+vz*vz);
  r = fmaxf(r, 1e-6f);
  float inv = 1.0f/r;
  float x=vx*inv, y=vy*inv, z=vz*inv;
  float* sh = shb + (size_t)e*9;
  const float s3=1.7320508075688772f, s15=3.872983346207417f, s5h=1.118033988749895f, s15h=1.9364916731037085f;
  sh[0]=1.0f;
  sh[1]=s3*y; sh[2]=s3*z; sh[3]=s3*x;
  sh[4]=s15*x*y; sh[5]=s15*y*z; sh[6]=s5h*(3.0f*z*z-1.0f); sh[7]=s15*x*z; sh[8]=s15h*(x*x-y*y);
  float u=r*0.1f;
  float cut=0.0f;
  if (u<1.0f){ float u2=u*u; float u5=u2*u2*u; cut = 1.0f - 21.0f*u5 + 35.0f*u5*u - 15.0f*u5*u2; }
  const float c0 = 0.4472135954999579f;
  const float PIF = 3.14159265358979323846f;
  float* ef = efb + (size_t)e*8;
  for (int j=0;j<8;j++)
    ef[j] = c0*sinf((float)(j+1)*PIF*r*0.1f)*inv*cut;
}

// ---------------- embedding ----------------
__global__ __launch_bounds__(256) void kembed(const float* __restrict__ x, const float* __restrict__ wemb,
                                              const float* __restrict__ bemb, float* __restrict__ h){
  int idx = blockIdx.x*256+threadIdx.x;
  if (idx>=NN*32) return;
  int n=idx>>5, k=idx&31;
  float a=bemb[k];
  for (int d=0;d<26;d++) a += x[n*26+d]*wemb[d*32+k];
  float* hp = h + (size_t)n*288 + k*9;
  hp[0]=a;
  #pragma unroll
  for (int c=1;c<9;c++) hp[c]=0.0f;
}

// ---------------- w2 transpose + bf16 cast ----------------
__global__ __launch_bounds__(256) void ktrans(const float* __restrict__ fc0_w2, const float* __restrict__ fcs_w2,
                                              ushortt* __restrict__ w2t0, ushortt* __restrict__ w2tH){
  int layer = blockIdx.z;
  int numel = (layer==0) ? 3072 : 11264;
  int c0 = blockIdx.x*32;
  if (c0 >= numel) return;
  const float* src = (layer==0) ? fc0_w2 : fcs_w2 + (size_t)(layer-1)*128*11264;
  ushortt* dst = (layer==0) ? w2t0 : w2tH + (size_t)(layer-1)*11264*128;
  int k0 = blockIdx.y*32;
  __shared__ float tile[32][33];
  int t = threadIdx.x;
  #pragma unroll
  for (int it=0; it<4; it++){
    int r = (t>>5) + it*8;
    tile[r][t&31] = src[(size_t)(k0+r)*numel + c0 + (t&31)];
  }
  __syncthreads();
  #pragma unroll
  for (int it=0; it<4; it++){
    int c = (t>>5) + it*8;
    int k = t&31;
    dst[(size_t)(c0+c)*128 + k0 + k] = f2bf(tile[k][c]);
  }
}

// ---------------- hidden MLP layer 1 -> bf16 (vectorized: 8 outputs/thread) ----------------
__global__ __launch_bounds__(256) void khid2(const float* __restrict__ efb, const float* __restrict__ w1,
                                             const float* __restrict__ b1, ushortt* __restrict__ hidbf){
  int idx = blockIdx.x*256+threadIdx.x;   // NE*16 total
  if (idx >= NE*16) return;
  int e = idx>>4, q = idx&15;
  int m0 = q*8;
  float efr[8];
  const float* ef = efb + (size_t)e*8;
  #pragma unroll
  for (int j=0;j<8;j++) efr[j]=ef[j];
  ushortt out8[8];
  #pragma unroll
  for (int mm=0;mm<8;mm++){
    int m = m0+mm;
    float a = b1[m];
    #pragma unroll
    for (int j=0;j<8;j++) a = fmaf(efr[j], w1[j*128+m], a);
    out8[mm] = f2bf(a>0.0f?a:0.0f);
  }
  *(short8*)(hidbf + (size_t)e*128 + m0) = *(const short8*)out8;
}

// ---------------- fused MFMA message kernel v9: register-double-buffered direct-B ----------------
// 256 threads / 4 waves; 64 edges/block; 16 chunks of 64 cols; B from L2 with 1-chunk prefetch;
// NO main-loop barriers.
__device__ __forceinline__ void loadB(short8 (&d)[4][4], const ushortt* bbase, int c){
  #pragma unroll
  for (int fn=0;fn<4;fn++){
    const ushortt* bp = bbase + (size_t)(c*64 + fn*16)*128;
    #pragma unroll
    for (int kk=0;kk<4;kk++) d[fn][kk] = *(const short8*)(bp + kk*32);
  }
}

template<int NO>
__global__ __launch_bounds__(256, 2) void kmsg9(
    const float* __restrict__ hc, const float* __restrict__ shb,
    const ushortt* __restrict__ hidbf, const ushortt* __restrict__ w2t,
    const float* __restrict__ b2, const float* __restrict__ cg,
    const int* __restrict__ src, float* __restrict__ msgp, int plist){
  int p = (plist >> (blockIdx.y*8)) & 0xFF;
  int e0 = blockIdx.x*64;
  int li=PATHS[p].li, ls=PATHS[p].ls;
  int n1=2*li+1, ns=2*ls+1;
  int lioff=loff_(li), lsoff=loff_(ls);
  int cgoff=PATHS[p].cgoff;
  int comp=PATHS[p].comp;

  __shared__ __align__(16) float sT[NO*2048];   // [u*NO+o][64e]; reused as write staging
  __shared__ __align__(16) float sCP[64*25];
  __shared__ __align__(16) float sSH[64*9];
  __shared__ __align__(16) float sB2[1024];
  __shared__ int sSRC[64];

  int t = threadIdx.x;
  int w = t>>6, l = t&63;

  // A-fragments direct to registers (wave w owns edge rows w*16..w*16+16)
  short8 av[4];
  {
    const ushortt* ap = hidbf + (size_t)(e0 + w*16 + (l&15))*128 + (l>>4)*8;
    #pragma unroll
    for (int kk=0;kk<4;kk++) av[kk] = *(const short8*)(ap + kk*32);
  }
  #pragma unroll
  for (int q=0;q<4;q++) sB2[t + q*256] = b2[p*1024 + t + q*256];
  if (t < 64) sSRC[t] = src[e0+t];
  for (int idx=t; idx<64*9; idx+=256) sSH[idx] = shb[(size_t)e0*9 + idx];
  __syncthreads();

  // cp[e][i][o] = sum_s CG[i,s,o]*sh[e][ls][s]
  for (int idx=t; idx<64*n1*NO; idx+=256){
    int e=idx/(n1*NO), r=idx%(n1*NO), i=r/NO, o=r%NO;
    float a=0.0f;
    for (int s=0;s<ns;s++) a += cg[cgoff + (i*ns+s)*NO+o]*sSH[e*9 + lsoff + s];
    sCP[e*25 + i*NO + o]=a;
  }
  __syncthreads();

  // t[u][o][e] = sum_i h[li][src[e]][u][i]*cp[e][i][o]
  for (int idx=t; idx<64*32; idx+=256){
    int e = idx&63, u = idx>>6;
    const float* hp = hc + (size_t)sSRC[e]*288 + u*9 + lioff;
    float hv[5];
    #pragma unroll
    for (int i=0;i<5;i++) hv[i] = hp[i];   // always in-bounds of node row
    #pragma unroll
    for (int o=0;o<NO;o++){
      float a=0.0f;
      #pragma unroll
      for (int i=0;i<5;i++) if (i<n1) a = fmaf(hv[i], sCP[e*25 + i*NO + o], a);
      sT[(u*NO+o)*64 + e] = a;
    }
  }
  __syncthreads();

  float macc[4][2][NO];
  #pragma unroll
  for (int r=0;r<4;r++)
    #pragma unroll
    for (int vh=0;vh<2;vh++)
      #pragma unroll
      for (int o=0;o<NO;o++) macc[r][vh][o]=0.0f;

  int e_idx = w*16 + (l>>4)*4;
  const ushortt* bbase = w2t + ((size_t)p*1024 + (l&15))*128 + (l>>4)*8;

  auto COMP = [&](int c, short8 (&bX)[4][4]){
    f32x4 acc[4];
    #pragma unroll
    for (int fn=0;fn<4;fn++)
      #pragma unroll
      for (int r=0;r<4;r++) acc[fn][r]=0.0f;
    __builtin_amdgcn_s_setprio(1);
    #pragma unroll
    for (int kk=0; kk<4; kk++)
      #pragma unroll
      for (int fn=0; fn<4; fn++)
        acc[fn] = __builtin_amdgcn_mfma_f32_16x16x32_bf16(av[kk], bX[fn][kk], acc[fn], 0,0,0);
    __builtin_amdgcn_s_setprio(0);
    #pragma unroll
    for (int uu=0;uu<2;uu++){
      int ug = c*2 + uu;
      f32x4 tv[NO];
      #pragma unroll
      for (int o=0;o<NO;o++) tv[o] = *(const f32x4*)&sT[(ug*NO+o)*64 + e_idx];
      #pragma unroll
      for (int vh=0;vh<2;vh++){
        int fn = uu*2+vh;
        float b2v = sB2[c*64 + fn*16 + (l&15)];
        #pragma unroll
        for (int r=0;r<4;r++){
          float Cv = acc[fn][r] + b2v;
          #pragma unroll
          for (int o=0;o<NO;o++) macc[r][vh][o] = fmaf(Cv, tv[o][r], macc[r][vh][o]);
        }
      }
    }
  };

  short8 bA[4][4], bB[4][4];
  loadB(bA, bbase, 0);
  sfor<8>([&](auto ccc){
    constexpr int cc = decltype(ccc)::v;
    loadB(bB, bbase, 2*cc+1);
    COMP(2*cc, bA);
    if constexpr (2*cc+2 < 16) loadB(bA, bbase, 2*cc+2);
    COMP(2*cc+1, bB);
  });
  __syncthreads();   // all waves done reading sT

  // ---- stage output into LDS (sT reused as sW), swizzled by e to spread banks ----
  float* sW = sT;
  #pragma unroll
  for (int r=0;r<4;r++){
    int e = e_idx + r;
    #pragma unroll
    for (int vh=0;vh<2;vh++){
      int v = vh*16 + (l&15);
      int g = v>>2;
      int addr = e*32 + (((g ^ (e&7)))<<2) + (v&3);
      #pragma unroll
      for (int o=0;o<NO;o++)
        sW[o*2048 + addr] = macc[r][vh][o];
    }
  }
  __syncthreads();
  // ---- stream out coalesced (full 128B lines) ----
  for (int j=t; j<NO*512; j+=256){
    int o = j>>9, q = j&511;
    int e = q>>3, gl = q&7;
    f32x4 vv = *(const f32x4*)&sW[o*2048 + e*32 + ((gl^(e&7))<<2)];
    *(f32x4*)(msgp + (size_t)(comp+o)*PLANE + (size_t)e0*32 + q*4) = vv;
  }
}

// ---------------- CSR build (once per forward) ----------------
__global__ __launch_bounds__(320) void kbuild(const int* __restrict__ dst, int* __restrict__ cnt, int* __restrict__ lst){
  int n = blockIdx.x;
  int t = threadIdx.x;
  __shared__ int s_dstl[NE];
  __shared__ int s_cnt[321];
  for (int idx=t; idx<NE; idx+=320) s_dstl[idx]=dst[idx];
  __syncthreads();
  const int per = NE/320;
  int start=t*per, end=start+per;
  int c=0;
  for (int e=start;e<end;++e) if (s_dstl[e]==n) c++;
  s_cnt[t+1]=c;
  if (t==0) s_cnt[0]=0;
  __syncthreads();
  if (t==0){ for (int i=1;i<=320;i++) s_cnt[i]+=s_cnt[i-1]; }
  __syncthreads();
  int pos = s_cnt[t];
  for (int e=start;e<end;++e) if (s_dstl[e]==n){ if (pos<CAP) lst[n*CAP+pos]=e; pos++; }
  if (t==0){ int M=s_cnt[320]; cnt[n]=(M<CAP)?M:CAP; }
}

// ---------------- gather via CSR (plane-major msg) ----------------
__global__ __launch_bounds__(320) void kgather2(const float* __restrict__ msgp, const int* __restrict__ cnt,
                                                const int* __restrict__ lst, float* __restrict__ mbuf, int full){
  int n = blockIdx.x;
  int t = threadIdx.x;
  if (t >= 288) return;
  int M = cnt[n];
  int jc = t>>5, k = t&31;
  float acc=0.0f;
  if (full){
    int pl0,pl1,pl2,pl3,np;
    if (jc==0){ pl0=0; pl1=12; pl2=29; pl3=0; np=3; }
    else if (jc<4){ int o=jc-1; pl0=1+o; pl1=9+o; pl2=18+o; pl3=26+o; np=4; }
    else { int o=jc-4; pl0=4+o; pl1=13+o; pl2=21+o; pl3=30+o; np=4; }
    for (int m=0;m<M;++m){
      int e = lst[n*CAP+m];
      int base = e*32 + k;
      float a = msgp[(size_t)pl0*PLANE + base] + msgp[(size_t)pl1*PLANE + base] + msgp[(size_t)pl2*PLANE + base];
      if (np==4) a += msgp[(size_t)pl3*PLANE + base];
      acc += a;
    }
  } else {
    for (int m=0;m<M;++m){
      int e = lst[n*CAP+m];
      acc += msgp[(size_t)jc*PLANE + e*32 + k];
    }
  }
  float norm = full ? (jc==0 ? 0.10206207261596577f : 0.08838834764831845f) : 0.17677669529663687f;
  mbuf[(size_t)n*288 + k*9 + jc] = acc*norm;
}

// ---------------- BN stats ----------------
__global__ __launch_bounds__(256) void kbn(const float* __restrict__ mbuf, float* __restrict__ stats){
  int k = blockIdx.x, t = threadIdx.x;
  float s0=0,sq0=0,sq1=0,sq2=0;
  for (int n=t;n<NN;n+=256){
    const float* mp = mbuf + (size_t)n*288 + k*9;
    float v0=mp[0]; s0+=v0; sq0+=v0*v0;
    float a=mp[1],b=mp[2],c=mp[3]; sq1+=a*a+b*b+c*c;
    float d=mp[4],e=mp[5],f=mp[6],g=mp[7],h=mp[8]; sq2+=d*d+e*e+f*f+g*g+h*h;
  }
  __shared__ float r[4][256];
  r[0][t]=s0; r[1][t]=sq0; r[2][t]=sq1; r[3][t]=sq2;
  __syncthreads();
  for (int s=128;s>0;s>>=1){
    if (t<s){ r[0][t]+=r[0][t+s]; r[1][t]+=r[1][t+s]; r[2][t]+=r[2][t+s]; r[3][t]+=r[3][t+s]; }
    __syncthreads();
  }
  if (t==0){
    float mu = r[0][0]/(float)NN;
    float var = r[1][0]/(float)NN - mu*mu;
    stats[k]      = mu;
    stats[32+k]   = rsqrtf(var + 1e-5f);
    stats[64+k]   = rsqrtf(r[2][0]/(float)NN + 1e-5f);
    stats[96+k]   = rsqrtf(r[3][0]/(float)NN + 1e-5f);
  }
}

// ---------------- tensor products, fully unrolled in registers ----------------
template<int CGA,int NA,int AO,int NB,int BO,int NO>
__device__ __forceinline__ void c2u(const float* __restrict__ cg, const float (&A)[9], const float (&B)[9], float (&out)[5]){
  #pragma unroll
  for (int o=0;o<NO;o++) out[o]=0.0f;
  #pragma unroll
  for (int i=0;i<NA;i++){
    #pragma unroll
    for (int j=0;j<NB;j++){
      float ab=A[AO+i]*B[BO+j];
      #pragma unroll
      for (int o=0;o<NO;o++) out[o]=fmaf(ab, cg[CGA+(i*NB+j)*NO+o], out[o]);
    }
  }
}
template<int CGA,int NA,int NB,int BO,int NO>
__device__ __forceinline__ void c2u5(const float* __restrict__ cg, const float (&Bb)[5], const float (&A)[9], float (&out)[5]){
  #pragma unroll
  for (int o=0;o<NO;o++) out[o]=0.0f;
  #pragma unroll
  for (int i=0;i<NA;i++){
    #pragma unroll
    for (int j=0;j<NB;j++){
      float ab=Bb[i]*A[BO+j];
      #pragma unroll
      for (int o=0;o<NO;o++) out[o]=fmaf(ab, cg[CGA+(i*NB+j)*NO+o], out[o]);
    }
  }
}

template<int LO>
__device__ __forceinline__ void do_lo(const float* __restrict__ cg, const float (&A)[9], float (&L)[9],
                                      const float* __restrict__ w1, const float* __restrict__ w2,
                                      const float* __restrict__ w3, int k){
  constexpr int NO=2*LO+1, AO=cloff(LO);
  float acc[5];
  float wc = w1[LO*32+k];
  #pragma unroll
  for (int o=0;o<NO;o++) acc[o]=wc*A[AO+o];
  sfor<nPR(LO)>([&](auto pc){
    constexpr int p = decltype(pc)::v;
    constexpr CPair P = getPR(LO,p);
    float tt[5];
    c2u<P.cga, 2*P.l1+1, cloff(P.l1), 2*P.l2+1, cloff(P.l2), NO>(cg, A, A, tt);
    float w = w2[(LO*4+p)*32+k];
    #pragma unroll
    for (int o=0;o<NO;o++) acc[o]=fmaf(w, tt[o], acc[o]);
  });
  sfor<nTR(LO)>([&](auto pc){
    constexpr int p = decltype(pc)::v;
    constexpr CTrip T = getTR(LO,p);
    constexpr int NL=2*T.L+1;
    float bb[5];
    c2u<T.cga, 2*T.l1+1, cloff(T.l1), 2*T.l2+1, cloff(T.l2), NL>(cg, A, A, bb);
    float tt[5];
    c2u5<T.cgb, NL, 2*T.l3+1, cloff(T.l3), NO>(cg, bb, A, tt);
    float w = w3[(LO*15+p)*32+k];
    #pragma unroll
    for (int o=0;o<NO;o++) acc[o]=fmaf(w, tt[o], acc[o]);
  });
  #pragma unroll
  for (int o=0;o<NO;o++) L[AO+o]=acc[o];
}

template<int LAST>
__global__ __launch_bounds__(256) void kprod3(const float* __restrict__ mbuf, const float* __restrict__ stats,
    const float* __restrict__ hc, float* __restrict__ hn,
    const float* __restrict__ bnw, const float* __restrict__ bnb,
    const float* __restrict__ w1, const float* __restrict__ w2, const float* __restrict__ w3,
    const float* __restrict__ plin, const float* __restrict__ cg, float* __restrict__ nodeout){
  int t = threadIdx.x;
  int nl = t>>5, k = t&31;
  int n = blockIdx.x*8 + nl;
  __shared__ float sL[8][32][9];
  float A[9], L[9];
  #pragma unroll
  for (int j=0;j<9;j++) L[j]=0.0f;
  const float* mp = mbuf + (size_t)n*288 + k*9;
  {
    float a0 = (mp[0]-stats[k])*stats[32+k]*bnw[k] + bnb[k];
    float f1 = stats[64+k]*bnw[32+k];
    float f2 = stats[96+k]*bnw[64+k];
    A[0]=a0;
    A[1]=mp[1]*f1; A[2]=mp[2]*f1; A[3]=mp[3]*f1;
    #pragma unroll
    for (int c=0;c<5;c++) A[4+c]=mp[4+c]*f2;
  }
  do_lo<0>(cg, A, L, w1, w2, w3, k);
  if constexpr (!LAST){
    do_lo<1>(cg, A, L, w1, w2, w3, k);
    do_lo<2>(cg, A, L, w1, w2, w3, k);
  }
  #pragma unroll
  for (int j=0;j<9;j++) sL[nl][k][j]=L[j];
  __syncthreads();

  if constexpr (!LAST){
    for (int idx=t; idx<8*288; idx+=256){
      int n2 = idx/288;
      int r  = idx%288;
      int jc = r>>5, v = r&31;
      int lo = (jc==0)?0:((jc<4)?1:2);
      float y=0.0f;
      const float* pl = plin + lo*1024 + v;
      for (int kk=0;kk<32;kk++)
        y = fmaf(sL[n2][kk][jc], pl[kk*32], y);
      int ng = blockIdx.x*8 + n2;
      y += hc[(size_t)ng*288 + v*9 + jc];
      hn[(size_t)ng*288 + v*9 + jc] = y;
    }
  } else {
    int n2 = t>>5, v = t&31;
    float y=0.0f;
    const float* pl = plin + v;
    for (int kk=0;kk<32;kk++)
      y = fmaf(sL[n2][kk][0], pl[kk*32], y);
    nodeout[(size_t)(blockIdx.x*8+n2)*32 + v] = y;
  }
}

// ---------------- graph segment sum (two-stage deterministic) ----------------
__global__ __launch_bounds__(256) void kgraphA(const float* __restrict__ nodeout, const int* __restrict__ batch,
                                               float* __restrict__ partial){
  int b = blockIdx.x;          // 125 blocks x 8 nodes
  int t = threadIdx.x;
  __shared__ float sv[8][32];
  __shared__ int   sg[8];
  int nl = t>>5, k = t&31;
  int n = b*8 + nl;
  sv[nl][k] = nodeout[(size_t)n*32 + k];
  if (k==0) sg[nl] = batch[n];
  __syncthreads();
  if (t < 128){
    int g = t>>5, kk = t&31;
    float acc=0.0f;
    #pragma unroll
    for (int j=0;j<8;j++) if (sg[j]==g) acc += sv[j][kk];
    partial[((size_t)b*4 + g)*32 + kk] = acc;
  }
}

__global__ __launch_bounds__(128) void kgraphB(const float* __restrict__ partial, float* __restrict__ gout){
  int t = threadIdx.x;
  int g = t>>5, k = t&31;
  float acc=0.0f;
  for (int b=0;b<125;b++) acc += partial[((size_t)b*4 + g)*32 + k];
  gout[g*32 + k] = acc;
}

// ---------------- launch ----------------
extern "C" void kernel_launch(void* const* d_in, const int* in_sizes, int n_in,
                              void* d_out, int out_size, void* d_ws, size_t ws_size,
                              hipStream_t stream) {
  const float* x      = (const float*)d_in[0];
  const float* pos    = (const float*)d_in[1];
  const int*   ei     = (const int*)d_in[2];
  const int*   batch  = (const int*)d_in[3];
  const float* w_emb  = (const float*)d_in[4];
  const float* b_emb  = (const float*)d_in[5];
  const float* fc0_w1 = (const float*)d_in[6];
  const float* fc0_b1 = (const float*)d_in[7];
  const float* fc0_w2 = (const float*)d_in[8];
  const float* fc0_b2 = (const float*)d_in[9];
  const float* fcs_w1 = (const float*)d_in[10];
  const float* fcs_b1 = (const float*)d_in[11];
  const float* fcs_w2 = (const float*)d_in[12];
  const float* fcs_b2 = (const float*)d_in[13];
  const float* bn_w   = (const float*)d_in[14];
  const float* bn_b   = (const float*)d_in[15];
  const float* pw1    = (const float*)d_in[16];
  const float* pw2    = (const float*)d_in[17];
  const float* pw3    = (const float*)d_in[18];
  const float* plin   = (const float*)d_in[19];

  double* cgtmp = (double*)d_ws;
  float*  F     = (float*)d_ws;
  float*  cgf   = F + 1456;
  float*  shb   = F + 1824;
  float*  efb   = F + 73824;
  float*  hA    = F + 137824;
  float*  hB    = F + 425824;
  float*  mbuf  = F + 713824;
  float*  stats = F + 1001824;
  float*  msgb  = F + 1001952;
  ushortt* hidbf = (ushortt*)(F + 9961952);
  ushortt* w2t0  = (ushortt*)(F + 10473952);
  ushortt* w2tH  = (ushortt*)(F + 10670560);
  int* csr_cnt = (int*)(F + 12833248);
  int* csr_lst = csr_cnt + 1024;
  float* partial = F + 12900000;   // 16000 floats

  float* nodeout = (float*)d_out;
  float* gout    = (float*)d_out + NN*32;

  kcg1<<<11,128,0,stream>>>(cgtmp);
  kcg2<<<1,64,0,stream>>>(cgtmp, cgf);
  kgeom<<<(NE+255)/256,256,0,stream>>>(pos, ei, shb, efb);
  kembed<<<(NN*32+255)/256,256,0,stream>>>(x, w_emb, b_emb, hA);
  ktrans<<<dim3(352,4,4),256,0,stream>>>(fc0_w2, fcs_w2, w2t0, w2tH);
  kbuild<<<NN,320,0,stream>>>(ei+NE, csr_cnt, csr_lst);

  float* hc = hA;
  float* hn = hB;
  for (int i=0;i<4;i++){
    const float *w1,*b1,*b2; const ushortt* w2t; int full;
    if (i==0){ w1=fc0_w1; b1=fc0_b1; w2t=w2t0; b2=fc0_b2; full=0; }
    else {
      int j=i-1;
      w1=fcs_w1 + (size_t)j*1024;
      b1=fcs_b1 + (size_t)j*128;
      w2t=w2tH + (size_t)j*11264*128;
      b2=fcs_b2 + (size_t)j*11264;
      full=1;
    }
    khid2<<<(NE*16+255)/256,256,0,stream>>>(efb, w1, b1, hidbf);
    if (full){
      kmsg9<1><<<dim3(125,3),256,0,stream>>>(hc, shb, hidbf, w2t, b2, cgf, ei, msgb, 0 | (4<<8) | (9<<16));
      kmsg9<3><<<dim3(125,4),256,0,stream>>>(hc, shb, hidbf, w2t, b2, cgf, ei, msgb, 1 | (3<<8) | (6<<16) | (8<<24));
      kmsg9<5><<<dim3(125,4),256,0,stream>>>(hc, shb, hidbf, w2t, b2, cgf, ei, msgb, 2 | (5<<8) | (7<<16) | (10<<24));
    } else {
      kmsg9<1><<<dim3(125,1),256,0,stream>>>(hc, shb, hidbf, w2t, b2, cgf, ei, msgb, 0);
      kmsg9<3><<<dim3(125,1),256,0,stream>>>(hc, shb, hidbf, w2t, b2, cgf, ei, msgb, 1);
      kmsg9<5><<<dim3(125,1),256,0,stream>>>(hc, shb, hidbf, w2t, b2, cgf, ei, msgb, 2);
    }
    kgather2<<<NN,320,0,stream>>>(msgb, csr_cnt, csr_lst, mbuf, full);
    kbn<<<32,256,0,stream>>>(mbuf, stats);
    int last = (i==3);
    const float* bw = bn_w + (size_t)i*96;
    const float* bb = bn_b + (size_t)i*32;
    const float* p1 = pw1 + (size_t)i*96;
    const float* p2 = pw2 + (size_t)i*384;
    const float* p3 = pw3 + (size_t)i*1440;
    const float* pl = plin + (size_t)i*3072;
    if (!last)
      kprod3<0><<<NN/8,256,0,stream>>>(mbuf, stats, hc, hn, bw, bb, p1, p2, p3, pl, cgf, nodeout);
    else
      kprod3<1><<<NN/8,256,0,stream>>>(mbuf, stats, hc, hn, bw, bb, p1, p2, p3, pl, cgf, nodeout);
    float* tmp=hc; hc=hn; hn=tmp;
  }
  kgraphA<<<125,256,0,stream>>>(nodeout, batch, partial);
  kgraphB<<<1,128,0,stream>>>(partial, gout);
}

// Round 13
// 602.096 us; speedup vs baseline: 1.6185x; 1.6185x over previous
//
#include <hip/hip_runtime.h>
#include <hip/hip_bf16.h>
#include <math.h>

#define NE 8000
#define NN 1000
#define CAP 64
#define PLANE 256000   // 8000*32

typedef unsigned short ushortt;
typedef __attribute__((ext_vector_type(8))) short short8;
typedef __attribute__((ext_vector_type(4))) float f32x4;

// ---------------- CG tables metadata ----------------
__device__ const int KEYL[11][3] = {{0,0,0},{0,1,1},{0,2,2},{1,0,1},{1,1,0},{1,1,2},{1,2,1},{2,0,2},{2,1,1},{2,2,0},{2,2,2}};
__device__ const int KEYOFF[12] = {0,1,10,35,44,53,98,143,168,213,238,363};

struct PathT { int li, ls, lo, cgoff, comp; };
__device__ const PathT PATHS[11] = {
 {0,0,0,  0, 0},{0,1,1,  1, 1},{0,2,2, 10, 4},{1,0,1, 35, 9},{1,1,0, 44,12},{1,1,2, 53,13},
 {1,2,1, 98,18},{2,0,2,143,21},{2,1,1,168,26},{2,2,0,213,29},{2,2,2,238,30}};

// ---- compile-time tables for the product kernel ----
struct CPair { int l1,l2,cga; };
struct CTrip { int l1,l2,L,cga,l3,cgb; };
constexpr CPair cPR0[3]={{0,0,0},{1,1,44},{2,2,213}};
constexpr CPair cPR1[4]={{0,1,1},{1,0,35},{1,2,98},{2,1,168}};
constexpr CPair cPR2[4]={{0,2,10},{1,1,53},{2,0,143},{2,2,238}};
constexpr CTrip cTR0[11]={
  {0,0,0,0,0,0},{1,1,0,44,0,0},{2,2,0,213,0,0},
  {0,1,1,1,1,44},{1,0,1,35,1,44},{1,2,1,98,1,44},{2,1,1,168,1,44},
  {0,2,2,10,2,213},{1,1,2,53,2,213},{2,0,2,143,2,213},{2,2,2,238,2,213}};
constexpr CTrip cTR1[15]={
  {0,0,0,0,1,1},{1,1,0,44,1,1},{2,2,0,213,1,1},
  {0,1,1,1,0,35},{1,0,1,35,0,35},{1,2,1,98,0,35},{2,1,1,168,0,35},
  {0,1,1,1,2,98},{1,0,1,35,2,98},{1,2,1,98,2,98},{2,1,1,168,2,98},
  {0,2,2,10,1,168},{1,1,2,53,1,168},{2,0,2,143,1,168},{2,2,2,238,1,168}};
constexpr CTrip cTR2[15]={
  {0,0,0,0,2,10},{1,1,0,44,2,10},{2,2,0,213,2,10},
  {0,1,1,1,1,53},{1,0,1,35,1,53},{1,2,1,98,1,53},{2,1,1,168,1,53},
  {0,2,2,10,0,143},{1,1,2,53,0,143},{2,0,2,143,0,143},{2,2,2,238,0,143},
  {0,2,2,10,2,238},{1,1,2,53,2,238},{2,0,2,143,2,238},{2,2,2,238,2,238}};
constexpr CPair getPR(int lo,int p){ return lo==0?cPR0[p]:(lo==1?cPR1[p]:cPR2[p]); }
constexpr CTrip getTR(int lo,int p){ return lo==0?cTR0[p]:(lo==1?cTR1[p]:cTR2[p]); }
constexpr int cloff(int l){ return l==0?0:(l==1?1:4); }
constexpr int nPR(int lo){ return lo==0?3:4; }
constexpr int nTR(int lo){ return lo==0?11:15; }

template<int I> struct ic_t { static constexpr int v = I; };
template<int N, int I=0, typename F>
__device__ __forceinline__ void sfor(F&& f){
  if constexpr (I < N){ f(ic_t<I>{}); sfor<N, I+1>((F&&)f); }
}

__device__ __forceinline__ int loff_(int l){ return l==0?0:(l==1?1:4); }

__device__ __forceinline__ ushortt f2bf(float x){
  union { float f; unsigned int u; } a; a.f = x;
  unsigned int r = a.u + 0x7FFFu + ((a.u >> 16) & 1u);
  return (ushortt)(r >> 16);
}

__device__ __forceinline__ void gload_lds16(const void* g, void* lds){
  __builtin_amdgcn_global_load_lds((const __attribute__((address_space(1))) void*)g,
                                   (__attribute__((address_space(3))) void*)lds, 16, 0, 0);
}

// ---------------- device CG math ----------------
__device__ double d_fact(int n){ double f=1.0; for(int i=2;i<=n;i++) f*=(double)i; return f; }

__device__ double d_cg(int j1,int m1,int j2,int m2,int J,int M){
  if (M != m1+m2 || J < abs(j1-j2) || J > j1+j2) return 0.0;
  double pre = sqrt((2.0*J+1.0)*d_fact(J+j1-j2)*d_fact(J-j1+j2)*d_fact(j1+j2-J)/d_fact(j1+j2+J+1));
  pre *= sqrt(d_fact(J+M)*d_fact(J-M)*d_fact(j1-m1)*d_fact(j1+m1)*d_fact(j2-m2)*d_fact(j2+m2));
  double s=0.0;
  for(int k=0;k<=j1+j2-J;k++){
    int d0=k, d1=j1+j2-J-k, d2=j1-m1-k, d3=j2+m2-k, d4=J-j2+m1+k, d5=J-j1-m2+k;
    if (d0<0||d1<0||d2<0||d3<0||d4<0||d5<0) continue;
    double den = d_fact(d0)*d_fact(d1)*d_fact(d2)*d_fact(d3)*d_fact(d4)*d_fact(d5);
    s += ((k&1)?-1.0:1.0)/den;
  }
  return pre*s;
}

__device__ void d_u(int l, int i, int j, double* re, double* im){
  int m = i - l;
  *re=0.0; *im=0.0;
  const double s2 = 0.70710678118654752440;
  double par = (m & 1) ? -1.0 : 1.0;
  if (m < 0){
    if (j == m + l)  *im += s2;
    if (j == -m + l) *im += -par*s2;
  } else if (m == 0){
    if (j == l) *re = 1.0;
  } else {
    if (j == -m + l) *re += s2;
    if (j == m + l)  *re += par*s2;
  }
}

__global__ __launch_bounds__(128) void kcg1(double* tmp){
  int key = blockIdx.x;
  int l1=KEYL[key][0], l2=KEYL[key][1], l3=KEYL[key][2];
  int n1=2*l1+1, n2=2*l2+1, n3=2*l3+1;
  int nel=n1*n2*n3;
  int t=threadIdx.x;
  if (t>=nel) return;
  int a=t/(n2*n3), b=(t/n3)%n2, c=t%n3;
  double sre=0.0, sim=0.0;
  for (int mi=0;mi<n1;mi++)
    for (int ni=0;ni<n2;ni++){
      int m3 = (mi-l1)+(ni-l2);
      int oi = m3 + l3;
      if (oi<0 || oi>=n3) continue;
      double tc = d_cg(l1,mi-l1,l2,ni-l2,l3,m3);
      if (tc==0.0) continue;
      double r1,i1,r2,i2,r3,i3;
      d_u(l1,a,mi,&r1,&i1);
      d_u(l2,b,ni,&r2,&i2);
      d_u(l3,c,oi,&r3,&i3);
      double rr = r1*r2 - i1*i2;
      double ri = r1*i2 + i1*r2;
      double fr = rr*r3 + ri*i3;
      double fi = ri*r3 - rr*i3;
      sre += fr*tc; sim += fi*tc;
    }
  tmp[(size_t)(KEYOFF[key]+t)*2]   = sre;
  tmp[(size_t)(KEYOFF[key]+t)*2+1] = sim;
}

__global__ __launch_bounds__(64) void kcg2(const double* tmp, float* cgf){
  int key=threadIdx.x;
  if (key>=11) return;
  int off=KEYOFF[key], n=KEYOFF[key+1]-off;
  double sre=0.0, sim=0.0;
  for (int i=0;i<n;i++){ sre += fabs(tmp[(size_t)(off+i)*2]); sim += fabs(tmp[(size_t)(off+i)*2+1]); }
  bool takeRe = (sre >= sim);
  for (int i=0;i<n;i++) cgf[off+i] = (float)(takeRe ? tmp[(size_t)(off+i)*2] : tmp[(size_t)(off+i)*2+1]);
}

// ---------------- edge geometry ----------------
__global__ __launch_bounds__(256) void kgeom(const float* __restrict__ pos, const int* __restrict__ ei,
                                             float* __restrict__ shb, float* __restrict__ efb){
  int e = blockIdx.x*256+threadIdx.x;
  if (e>=NE) return;
  int s=ei[e], d=ei[NE+e];
  float vx=pos[s*3]-pos[d*3], vy=pos[s*3+1]-pos[d*3+1], vz=pos[s*3+2]-pos[d*3+2];
  float r = sqrtf(vx*vx+vy*vy+vz*vz);
  r = fmaxf(r, 1e-6f);
  float inv = 1.0f/r;
  float x=vx*inv, y=vy*inv, z=vz*inv;
  float* sh = shb + (size_t)e*9;
  const float s3=1.7320508075688772f, s15=3.872983346207417f, s5h=1.118033988749895f, s15h=1.9364916731037085f;
  sh[0]=1.0f;
  sh[1]=s3*y; sh[2]=s3*z; sh[3]=s3*x;
  sh[4]=s15*x*y; sh[5]=s15*y*z; sh[6]=s5h*(3.0f*z*z-1.0f); sh[7]=s15*x*z; sh[8]=s15h*(x*x-y*y);
  float u=r*0.1f;
  float cut=0.0f;
  if (u<1.0f){ float u2=u*u; float u5=u2*u2*u; cut = 1.0f - 21.0f*u5 + 35.0f*u5*u - 15.0f*u5*u2; }
  const float c0 = 0.4472135954999579f;
  const float PIF = 3.14159265358979323846f;
  float* ef = efb + (size_t)e*8;
  for (int j=0;j<8;j++)
    ef[j] = c0*sinf((float)(j+1)*PIF*r*0.1f)*inv*cut;
}

// ---------------- embedding ----------------
__global__ __launch_bounds__(256) void kembed(const float* __restrict__ x, const float* __restrict__ wemb,
                                              const float* __restrict__ bemb, float* __restrict__ h){
  int idx = blockIdx.x*256+threadIdx.x;
  if (idx>=NN*32) return;
  int n=idx>>5, k=idx&31;
  float a=bemb[k];
  for (int d=0;d<26;d++) a += x[n*26+d]*wemb[d*32+k];
  float* hp = h + (size_t)n*288 + k*9;
  hp[0]=a;
  #pragma unroll
  for (int c=1;c<9;c++) hp[c]=0.0f;
}

// ---------------- w2 transpose + bf16 cast ----------------
__global__ __launch_bounds__(256) void ktrans(const float* __restrict__ fc0_w2, const float* __restrict__ fcs_w2,
                                              ushortt* __restrict__ w2t0, ushortt* __restrict__ w2tH){
  int layer = blockIdx.z;
  int numel = (layer==0) ? 3072 : 11264;
  int c0 = blockIdx.x*32;
  if (c0 >= numel) return;
  const float* src = (layer==0) ? fc0_w2 : fcs_w2 + (size_t)(layer-1)*128*11264;
  ushortt* dst = (layer==0) ? w2t0 : w2tH + (size_t)(layer-1)*11264*128;
  int k0 = blockIdx.y*32;
  __shared__ float tile[32][33];
  int t = threadIdx.x;
  #pragma unroll
  for (int it=0; it<4; it++){
    int r = (t>>5) + it*8;
    tile[r][t&31] = src[(size_t)(k0+r)*numel + c0 + (t&31)];
  }
  __syncthreads();
  #pragma unroll
  for (int it=0; it<4; it++){
    int c = (t>>5) + it*8;
    int k = t&31;
    dst[(size_t)(c0+c)*128 + k0 + k] = f2bf(tile[k][c]);
  }
}

// ---------------- hidden MLP layer 1 -> bf16 (vectorized: 8 outputs/thread) ----------------
__global__ __launch_bounds__(256) void khid2(const float* __restrict__ efb, const float* __restrict__ w1,
                                             const float* __restrict__ b1, ushortt* __restrict__ hidbf){
  int idx = blockIdx.x*256+threadIdx.x;   // NE*16 total
  if (idx >= NE*16) return;
  int e = idx>>4, q = idx&15;
  int m0 = q*8;
  float efr[8];
  const float* ef = efb + (size_t)e*8;
  #pragma unroll
  for (int j=0;j<8;j++) efr[j]=ef[j];
  ushortt out8[8];
  #pragma unroll
  for (int mm=0;mm<8;mm++){
    int m = m0+mm;
    float a = b1[m];
    #pragma unroll
    for (int j=0;j<8;j++) a = fmaf(efr[j], w1[j*128+m], a);
    out8[mm] = f2bf(a>0.0f?a:0.0f);
  }
  *(short8*)(hidbf + (size_t)e*128 + m0) = *(const short8*)out8;
}

// ---------------- fused MFMA message kernel v10: kmsg5 + counted-vmcnt raw-barrier pipeline ----------------
template<int NO>
__global__ __launch_bounds__(256, (NO==1?3:2)) void kmsg10(
    const float* __restrict__ hc, const float* __restrict__ shb,
    const ushortt* __restrict__ hidbf, const ushortt* __restrict__ w2t,
    const float* __restrict__ b2, const float* __restrict__ cg,
    const int* __restrict__ src, float* __restrict__ msgp, int plist){
  int p = (plist >> (blockIdx.y*8)) & 0xFF;
  int e0 = blockIdx.x*64;
  int li=PATHS[p].li, ls=PATHS[p].ls;
  int n1=2*li+1, ns=2*ls+1;
  int lioff=loff_(li), lsoff=loff_(ls);
  int cgoff=PATHS[p].cgoff;
  int comp=PATHS[p].comp;

  __shared__ __align__(16) ushortt sB[2][64*128];   // 32 KB
  __shared__ __align__(16) float   sT[NO*2048];     // NO*8 KB; reused as write staging
  __shared__ __align__(16) float   sB2[1024];       // 4 KB
  __shared__ int     sSRC[64];
  float* ov  = (float*)&sB[1][0];   // overlay: dead before chunk-1 data is consumed? NOTE: chunk1 now staged early,
  // so scratch must NOT overlap sB[1]. Use tail of sT instead is also unsafe (sT built in phase 2).
  // -> use dedicated small scratch:
  __shared__ __align__(16) float sCPb[64*25];
  __shared__ __align__(16) float sSHb[64*9];
  float* sCP = sCPb;
  float* sSH = sSHb;
  (void)ov;

  int t = threadIdx.x;
  int w = t>>6, l = t&63;

  // stage chunks 0 and 1
  #pragma unroll
  for (int q=0;q<4;q++){
    int R0 = w*16 + q*4;
    int row = R0 + (l>>4);
    int ks = ((l&15)*8) ^ ((row&7)<<3);
    gload_lds16(w2t + (size_t)(p*1024 + row)*128 + ks, &sB[0][R0*128]);
  }
  #pragma unroll
  for (int q=0;q<4;q++){
    int R0 = w*16 + q*4;
    int row = R0 + (l>>4);
    int ks = ((l&15)*8) ^ ((row&7)<<3);
    gload_lds16(w2t + (size_t)(p*1024 + 64 + row)*128 + ks, &sB[1][R0*128]);
  }
  // A-fragments direct to registers
  short8 av[4];
  {
    const ushortt* ap = hidbf + (size_t)(e0 + w*16 + (l&15))*128 + (l>>4)*8;
    #pragma unroll
    for (int kk=0;kk<4;kk++) av[kk] = *(const short8*)(ap + kk*32);
  }
  #pragma unroll
  for (int q=0;q<4;q++) sB2[t + q*256] = b2[p*1024 + t + q*256];
  if (t < 64) sSRC[t] = src[e0+t];
  for (int idx=t; idx<64*9; idx+=256) sSH[idx] = shb[(size_t)e0*9 + idx];
  __syncthreads();

  // cp[e][i][o] = sum_s CG[i,s,o]*sh[e][ls][s]
  for (int idx=t; idx<64*n1*NO; idx+=256){
    int e=idx/(n1*NO), r=idx%(n1*NO), i=r/NO, o=r%NO;
    float a=0.0f;
    for (int s=0;s<ns;s++) a += cg[cgoff + (i*ns+s)*NO+o]*sSH[e*9 + lsoff + s];
    sCP[e*25 + i*NO + o]=a;
  }
  __syncthreads();

  // t[u][o][e]
  for (int idx=t; idx<64*32; idx+=256){
    int e = idx&63, u = idx>>6;
    const float* hp = hc + (size_t)sSRC[e]*288 + u*9 + lioff;
    float hv[5];
    #pragma unroll
    for (int i=0;i<5;i++) hv[i] = hp[i];
    #pragma unroll
    for (int o=0;o<NO;o++){
      float a=0.0f;
      #pragma unroll
      for (int i=0;i<5;i++) if (i<n1) a = fmaf(hv[i], sCP[e*25 + i*NO + o], a);
      sT[(u*NO+o)*64 + e] = a;
    }
  }
  __syncthreads();   // drains chunk 0+1 staging too (compiler full drain, once)

  float macc[4][2][NO];
  #pragma unroll
  for (int r=0;r<4;r++)
    #pragma unroll
    for (int vh=0;vh<2;vh++)
      #pragma unroll
      for (int o=0;o<NO;o++) macc[r][vh][o]=0.0f;

  int e_idx = w*16 + (l>>4)*4;

  for (int c=0;c<16;c++){
    int buf = c&1;
    // chunk c staged? (c,c+1 prefetched; after the full drain at loop entry the first two are resident;
    // steady-state: c's loads are the oldest 4 of <=8 outstanding)
    if (c<15) { asm volatile("s_waitcnt vmcnt(4)" ::: "memory"); }
    else      { asm volatile("s_waitcnt vmcnt(0)" ::: "memory"); }
    asm volatile("s_barrier" ::: "memory");
    // MFMA: C[64 x 64chunk]; wave w rows [w*16, w*16+16)
    f32x4 acc[4];
    #pragma unroll
    for (int fn=0;fn<4;fn++)
      #pragma unroll
      for (int r=0;r<4;r++) acc[fn][r]=0.0f;
    __builtin_amdgcn_s_setprio(1);
    #pragma unroll
    for (int kk=0; kk<4; kk++){
      #pragma unroll
      for (int fn=0; fn<4; fn++){
        int brow = fn*16 + (l&15);
        int kb = (kk*32 + (l>>4)*8) ^ ((brow&7)<<3);
        short8 bv = *(const short8*)&sB[buf][brow*128 + kb];
        acc[fn] = __builtin_amdgcn_mfma_f32_16x16x32_bf16(av[kk], bv, acc[fn], 0,0,0);
      }
    }
    __builtin_amdgcn_s_setprio(0);
    // in-register contraction: u-window = {2c, 2c+1}
    #pragma unroll
    for (int uu=0;uu<2;uu++){
      int ug = c*2 + uu;
      f32x4 tv[NO];
      #pragma unroll
      for (int o=0;o<NO;o++) tv[o] = *(const f32x4*)&sT[(ug*NO+o)*64 + e_idx];
      #pragma unroll
      for (int vh=0;vh<2;vh++){
        int fn = uu*2+vh;
        float b2v = sB2[c*64 + fn*16 + (l&15)];
        #pragma unroll
        for (int r=0;r<4;r++){
          float Cv = acc[fn][r] + b2v;
          #pragma unroll
          for (int o=0;o<NO;o++) macc[r][vh][o] = fmaf(Cv, tv[o][r], macc[r][vh][o]);
        }
      }
    }
    asm volatile("s_barrier" ::: "memory");   // all waves done reading sB[buf]
    if (c+2<16){
      #pragma unroll
      for (int q=0;q<4;q++){
        int R0 = w*16 + q*4;
        int row = R0 + (l>>4);
        int ks = ((l&15)*8) ^ ((row&7)<<3);
        gload_lds16(w2t + (size_t)(p*1024 + (c+2)*64 + row)*128 + ks, &sB[buf][R0*128]);
      }
    }
  }

  // ---- stage output into LDS (sT reused as sW), swizzled by e to spread banks ----
  float* sW = sT;
  #pragma unroll
  for (int r=0;r<4;r++){
    int e = e_idx + r;
    #pragma unroll
    for (int vh=0;vh<2;vh++){
      int v = vh*16 + (l&15);
      int g = v>>2;
      int addr = e*32 + (((g ^ (e&7)))<<2) + (v&3);
      #pragma unroll
      for (int o=0;o<NO;o++)
        sW[o*2048 + addr] = macc[r][vh][o];
    }
  }
  __syncthreads();
  // ---- stream out coalesced (full 128B lines) ----
  for (int j=t; j<NO*512; j+=256){
    int o = j>>9, q = j&511;
    int e = q>>3, gl = q&7;
    f32x4 vv = *(const f32x4*)&sW[o*2048 + e*32 + ((gl^(e&7))<<2)];
    *(f32x4*)(msgp + (size_t)(comp+o)*PLANE + (size_t)e0*32 + q*4) = vv;
  }
}

// ---------------- CSR build (once per forward) ----------------
__global__ __launch_bounds__(320) void kbuild(const int* __restrict__ dst, int* __restrict__ cnt, int* __restrict__ lst){
  int n = blockIdx.x;
  int t = threadIdx.x;
  __shared__ int s_dstl[NE];
  __shared__ int s_cnt[321];
  for (int idx=t; idx<NE; idx+=320) s_dstl[idx]=dst[idx];
  __syncthreads();
  const int per = NE/320;
  int start=t*per, end=start+per;
  int c=0;
  for (int e=start;e<end;++e) if (s_dstl[e]==n) c++;
  s_cnt[t+1]=c;
  if (t==0) s_cnt[0]=0;
  __syncthreads();
  if (t==0){ for (int i=1;i<=320;i++) s_cnt[i]+=s_cnt[i-1]; }
  __syncthreads();
  int pos = s_cnt[t];
  for (int e=start;e<end;++e) if (s_dstl[e]==n){ if (pos<CAP) lst[n*CAP+pos]=e; pos++; }
  if (t==0){ int M=s_cnt[320]; cnt[n]=(M<CAP)?M:CAP; }
}

// ---------------- gather via CSR (plane-major msg) ----------------
__global__ __launch_bounds__(320) void kgather2(const float* __restrict__ msgp, const int* __restrict__ cnt,
                                                const int* __restrict__ lst, float* __restrict__ mbuf, int full){
  int n = blockIdx.x;
  int t = threadIdx.x;
  if (t >= 288) return;
  int M = cnt[n];
  int jc = t>>5, k = t&31;
  float acc=0.0f;
  if (full){
    int pl0,pl1,pl2,pl3,np;
    if (jc==0){ pl0=0; pl1=12; pl2=29; pl3=0; np=3; }
    else if (jc<4){ int o=jc-1; pl0=1+o; pl1=9+o; pl2=18+o; pl3=26+o; np=4; }
    else { int o=jc-4; pl0=4+o; pl1=13+o; pl2=21+o; pl3=30+o; np=4; }
    for (int m=0;m<M;++m){
      int e = lst[n*CAP+m];
      int base = e*32 + k;
      float a = msgp[(size_t)pl0*PLANE + base] + msgp[(size_t)pl1*PLANE + base] + msgp[(size_t)pl2*PLANE + base];
      if (np==4) a += msgp[(size_t)pl3*PLANE + base];
      acc += a;
    }
  } else {
    for (int m=0;m<M;++m){
      int e = lst[n*CAP+m];
      acc += msgp[(size_t)jc*PLANE + e*32 + k];
    }
  }
  float norm = full ? (jc==0 ? 0.10206207261596577f : 0.08838834764831845f) : 0.17677669529663687f;
  mbuf[(size_t)n*288 + k*9 + jc] = acc*norm;
}

// ---------------- BN stats ----------------
__global__ __launch_bounds__(256) void kbn(const float* __restrict__ mbuf, float* __restrict__ stats){
  int k = blockIdx.x, t = threadIdx.x;
  float s0=0,sq0=0,sq1=0,sq2=0;
  for (int n=t;n<NN;n+=256){
    const float* mp = mbuf + (size_t)n*288 + k*9;
    float v0=mp[0]; s0+=v0; sq0+=v0*v0;
    float a=mp[1],b=mp[2],c=mp[3]; sq1+=a*a+b*b+c*c;
    float d=mp[4],e=mp[5],f=mp[6],g=mp[7],h=mp[8]; sq2+=d*d+e*e+f*f+g*g+h*h;
  }
  __shared__ float r[4][256];
  r[0][t]=s0; r[1][t]=sq0; r[2][t]=sq1; r[3][t]=sq2;
  __syncthreads();
  for (int s=128;s>0;s>>=1){
    if (t<s){ r[0][t]+=r[0][t+s]; r[1][t]+=r[1][t+s]; r[2][t]+=r[2][t+s]; r[3][t]+=r[3][t+s]; }
    __syncthreads();
  }
  if (t==0){
    float mu = r[0][0]/(float)NN;
    float var = r[1][0]/(float)NN - mu*mu;
    stats[k]      = mu;
    stats[32+k]   = rsqrtf(var + 1e-5f);
    stats[64+k]   = rsqrtf(r[2][0]/(float)NN + 1e-5f);
    stats[96+k]   = rsqrtf(r[3][0]/(float)NN + 1e-5f);
  }
}

// ---------------- tensor products, fully unrolled in registers ----------------
template<int CGA,int NA,int AO,int NB,int BO,int NO>
__device__ __forceinline__ void c2u(const float* __restrict__ cg, const float (&A)[9], const float (&B)[9], float (&out)[5]){
  #pragma unroll
  for (int o=0;o<NO;o++) out[o]=0.0f;
  #pragma unroll
  for (int i=0;i<NA;i++){
    #pragma unroll
    for (int j=0;j<NB;j++){
      float ab=A[AO+i]*B[BO+j];
      #pragma unroll
      for (int o=0;o<NO;o++) out[o]=fmaf(ab, cg[CGA+(i*NB+j)*NO+o], out[o]);
    }
  }
}
template<int CGA,int NA,int NB,int BO,int NO>
__device__ __forceinline__ void c2u5(const float* __restrict__ cg, const float (&Bb)[5], const float (&A)[9], float (&out)[5]){
  #pragma unroll
  for (int o=0;o<NO;o++) out[o]=0.0f;
  #pragma unroll
  for (int i=0;i<NA;i++){
    #pragma unroll
    for (int j=0;j<NB;j++){
      float ab=Bb[i]*A[BO+j];
      #pragma unroll
      for (int o=0;o<NO;o++) out[o]=fmaf(ab, cg[CGA+(i*NB+j)*NO+o], out[o]);
    }
  }
}

template<int LO>
__device__ __forceinline__ void do_lo(const float* __restrict__ cg, const float (&A)[9], float (&L)[9],
                                      const float* __restrict__ w1, const float* __restrict__ w2,
                                      const float* __restrict__ w3, int k){
  constexpr int NO=2*LO+1, AO=cloff(LO);
  float acc[5];
  float wc = w1[LO*32+k];
  #pragma unroll
  for (int o=0;o<NO;o++) acc[o]=wc*A[AO+o];
  sfor<nPR(LO)>([&](auto pc){
    constexpr int p = decltype(pc)::v;
    constexpr CPair P = getPR(LO,p);
    float tt[5];
    c2u<P.cga, 2*P.l1+1, cloff(P.l1), 2*P.l2+1, cloff(P.l2), NO>(cg, A, A, tt);
    float w = w2[(LO*4+p)*32+k];
    #pragma unroll
    for (int o=0;o<NO;o++) acc[o]=fmaf(w, tt[o], acc[o]);
  });
  sfor<nTR(LO)>([&](auto pc){
    constexpr int p = decltype(pc)::v;
    constexpr CTrip T = getTR(LO,p);
    constexpr int NL=2*T.L+1;
    float bb[5];
    c2u<T.cga, 2*T.l1+1, cloff(T.l1), 2*T.l2+1, cloff(T.l2), NL>(cg, A, A, bb);
    float tt[5];
    c2u5<T.cgb, NL, 2*T.l3+1, cloff(T.l3), NO>(cg, bb, A, tt);
    float w = w3[(LO*15+p)*32+k];
    #pragma unroll
    for (int o=0;o<NO;o++) acc[o]=fmaf(w, tt[o], acc[o]);
  });
  #pragma unroll
  for (int o=0;o<NO;o++) L[AO+o]=acc[o];
}

template<int LAST>
__global__ __launch_bounds__(256) void kprod3(const float* __restrict__ mbuf, const float* __restrict__ stats,
    const float* __restrict__ hc, float* __restrict__ hn,
    const float* __restrict__ bnw, const float* __restrict__ bnb,
    const float* __restrict__ w1, const float* __restrict__ w2, const float* __restrict__ w3,
    const float* __restrict__ plin, const float* __restrict__ cg, float* __restrict__ nodeout){
  int t = threadIdx.x;
  int nl = t>>5, k = t&31;
  int n = blockIdx.x*8 + nl;
  __shared__ float sL[8][32][9];
  float A[9], L[9];
  #pragma unroll
  for (int j=0;j<9;j++) L[j]=0.0f;
  const float* mp = mbuf + (size_t)n*288 + k*9;
  {
    float a0 = (mp[0]-stats[k])*stats[32+k]*bnw[k] + bnb[k];
    float f1 = stats[64+k]*bnw[32+k];
    float f2 = stats[96+k]*bnw[64+k];
    A[0]=a0;
    A[1]=mp[1]*f1; A[2]=mp[2]*f1; A[3]=mp[3]*f1;
    #pragma unroll
    for (int c=0;c<5;c++) A[4+c]=mp[4+c]*f2;
  }
  do_lo<0>(cg, A, L, w1, w2, w3, k);
  if constexpr (!LAST){
    do_lo<1>(cg, A, L, w1, w2, w3, k);
    do_lo<2>(cg, A, L, w1, w2, w3, k);
  }
  #pragma unroll
  for (int j=0;j<9;j++) sL[nl][k][j]=L[j];
  __syncthreads();

  if constexpr (!LAST){
    for (int idx=t; idx<8*288; idx+=256){
      int n2 = idx/288;
      int r  = idx%288;
      int jc = r>>5, v = r&31;
      int lo = (jc==0)?0:((jc<4)?1:2);
      float y=0.0f;
      const float* pl = plin + lo*1024 + v;
      for (int kk=0;kk<32;kk++)
        y = fmaf(sL[n2][kk][jc], pl[kk*32], y);
      int ng = blockIdx.x*8 + n2;
      y += hc[(size_t)ng*288 + v*9 + jc];
      hn[(size_t)ng*288 + v*9 + jc] = y;
    }
  } else {
    int n2 = t>>5, v = t&31;
    float y=0.0f;
    const float* pl = plin + v;
    for (int kk=0;kk<32;kk++)
      y = fmaf(sL[n2][kk][0], pl[kk*32], y);
    nodeout[(size_t)(blockIdx.x*8+n2)*32 + v] = y;
  }
}

// ---------------- graph segment sum (two-stage deterministic) ----------------
__global__ __launch_bounds__(256) void kgraphA(const float* __restrict__ nodeout, const int* __restrict__ batch,
                                               float* __restrict__ partial){
  int b = blockIdx.x;          // 125 blocks x 8 nodes
  int t = threadIdx.x;
  __shared__ float sv[8][32];
  __shared__ int   sg[8];
  int nl = t>>5, k = t&31;
  int n = b*8 + nl;
  sv[nl][k] = nodeout[(size_t)n*32 + k];
  if (k==0) sg[nl] = batch[n];
  __syncthreads();
  if (t < 128){
    int g = t>>5, kk = t&31;
    float acc=0.0f;
    #pragma unroll
    for (int j=0;j<8;j++) if (sg[j]==g) acc += sv[j][kk];
    partial[((size_t)b*4 + g)*32 + kk] = acc;
  }
}

__global__ __launch_bounds__(128) void kgraphB(const float* __restrict__ partial, float* __restrict__ gout){
  int t = threadIdx.x;
  int g = t>>5, k = t&31;
  float acc=0.0f;
  for (int b=0;b<125;b++) acc += partial[((size_t)b*4 + g)*32 + k];
  gout[g*32 + k] = acc;
}

// ---------------- launch ----------------
extern "C" void kernel_launch(void* const* d_in, const int* in_sizes, int n_in,
                              void* d_out, int out_size, void* d_ws, size_t ws_size,
                              hipStream_t stream) {
  const float* x      = (const float*)d_in[0];
  const float* pos    = (const float*)d_in[1];
  const int*   ei     = (const int*)d_in[2];
  const int*   batch  = (const int*)d_in[3];
  const float* w_emb  = (const float*)d_in[4];
  const float* b_emb  = (const float*)d_in[5];
  const float* fc0_w1 = (const float*)d_in[6];
  const float* fc0_b1 = (const float*)d_in[7];
  const float* fc0_w2 = (const float*)d_in[8];
  const float* fc0_b2 = (const float*)d_in[9];
  const float* fcs_w1 = (const float*)d_in[10];
  const float* fcs_b1 = (const float*)d_in[11];
  const float* fcs_w2 = (const float*)d_in[12];
  const float* fcs_b2 = (const float*)d_in[13];
  const float* bn_w   = (const float*)d_in[14];
  const float* bn_b   = (const float*)d_in[15];
  const float* pw1    = (const float*)d_in[16];
  const float* pw2    = (const float*)d_in[17];
  const float* pw3    = (const float*)d_in[18];
  const float* plin   = (const float*)d_in[19];

  double* cgtmp = (double*)d_ws;
  float*  F     = (float*)d_ws;
  float*  cgf   = F + 1456;
  float*  shb   = F + 1824;
  float*  efb   = F + 73824;
  float*  hA    = F + 137824;
  float*  hB    = F + 425824;
  float*  mbuf  = F + 713824;
  float*  stats = F + 1001824;
  float*  msgb  = F + 1001952;
  ushortt* hidbf = (ushortt*)(F + 9961952);
  ushortt* w2t0  = (ushortt*)(F + 10473952);
  ushortt* w2tH  = (ushortt*)(F + 10670560);
  int* csr_cnt = (int*)(F + 12833248);
  int* csr_lst = csr_cnt + 1024;
  float* partial = F + 12900000;   // 16000 floats

  float* nodeout = (float*)d_out;
  float* gout    = (float*)d_out + NN*32;

  kcg1<<<11,128,0,stream>>>(cgtmp);
  kcg2<<<1,64,0,stream>>>(cgtmp, cgf);
  kgeom<<<(NE+255)/256,256,0,stream>>>(pos, ei, shb, efb);
  kembed<<<(NN*32+255)/256,256,0,stream>>>(x, w_emb, b_emb, hA);
  ktrans<<<dim3(352,4,4),256,0,stream>>>(fc0_w2, fcs_w2, w2t0, w2tH);
  kbuild<<<NN,320,0,stream>>>(ei+NE, csr_cnt, csr_lst);

  float* hc = hA;
  float* hn = hB;
  for (int i=0;i<4;i++){
    const float *w1,*b1,*b2; const ushortt* w2t; int full;
    if (i==0){ w1=fc0_w1; b1=fc0_b1; w2t=w2t0; b2=fc0_b2; full=0; }
    else {
      int j=i-1;
      w1=fcs_w1 + (size_t)j*1024;
      b1=fcs_b1 + (size_t)j*128;
      w2t=w2tH + (size_t)j*11264*128;
      b2=fcs_b2 + (size_t)j*11264;
      full=1;
    }
    khid2<<<(NE*16+255)/256,256,0,stream>>>(efb, w1, b1, hidbf);
    if (full){
      kmsg10<1><<<dim3(125,3),256,0,stream>>>(hc, shb, hidbf, w2t, b2, cgf, ei, msgb, 0 | (4<<8) | (9<<16));
      kmsg10<3><<<dim3(125,4),256,0,stream>>>(hc, shb, hidbf, w2t, b2, cgf, ei, msgb, 1 | (3<<8) | (6<<16) | (8<<24));
      kmsg10<5><<<dim3(125,4),256,0,stream>>>(hc, shb, hidbf, w2t, b2, cgf, ei, msgb, 2 | (5<<8) | (7<<16) | (10<<24));
    } else {
      kmsg10<1><<<dim3(125,1),256,0,stream>>>(hc, shb, hidbf, w2t, b2, cgf, ei, msgb, 0);
      kmsg10<3><<<dim3(125,1),256,0,stream>>>(hc, shb, hidbf, w2t, b2, cgf, ei, msgb, 1);
      kmsg10<5><<<dim3(125,1),256,0,stream>>>(hc, shb, hidbf, w2t, b2, cgf, ei, msgb, 2);
    }
    kgather2<<<NN,320,0,stream>>>(msgb, csr_cnt, csr_lst, mbuf, full);
    kbn<<<32,256,0,stream>>>(mbuf, stats);
    int last = (i==3);
    const float* bw = bn_w + (size_t)i*96;
    const float* bb = bn_b + (size_t)i*32;
    const float* p1 = pw1 + (size_t)i*96;
    const float* p2 = pw2 + (size_t)i*384;
    const float* p3 = pw3 + (size_t)i*1440;
    const float* pl = plin + (size_t)i*3072;
    if (!last)
      kprod3<0><<<NN/8,256,0,stream>>>(mbuf, stats, hc, hn, bw, bb, p1, p2, p3, pl, cgf, nodeout);
    else
      kprod3<1><<<NN/8,256,0,stream>>>(mbuf, stats, hc, hn, bw, bb, p1, p2, p3, pl, cgf, nodeout);
    float* tmp=hc; hc=hn; hn=tmp;
  }
  kgraphA<<<125,256,0,stream>>>(nodeout, batch, partial);
  kgraphB<<<1,128,0,stream>>>(partial, gout);
}

// Round 15
// 584.859 us; speedup vs baseline: 1.6662x; 1.0295x over previous
//
#include <hip/hip_runtime.h>
#include <hip/hip_bf16.h>
#include <math.h>

#define NE 8000
#define NN 1000
#define CAP 64
#define PLANE 256000   // 8000*32

typedef unsigned short ushortt;
typedef __attribute__((ext_vector_type(8))) short short8;
typedef __attribute__((ext_vector_type(4))) float f32x4;

// ---------------- CG tables metadata ----------------
__device__ const int KEYL[11][3] = {{0,0,0},{0,1,1},{0,2,2},{1,0,1},{1,1,0},{1,1,2},{1,2,1},{2,0,2},{2,1,1},{2,2,0},{2,2,2}};
__device__ const int KEYOFF[12] = {0,1,10,35,44,53,98,143,168,213,238,363};

struct PathT { int li, ls, lo, cgoff, comp; };
__device__ const PathT PATHS[11] = {
 {0,0,0,  0, 0},{0,1,1,  1, 1},{0,2,2, 10, 4},{1,0,1, 35, 9},{1,1,0, 44,12},{1,1,2, 53,13},
 {1,2,1, 98,18},{2,0,2,143,21},{2,1,1,168,26},{2,2,0,213,29},{2,2,2,238,30}};

// ---- compile-time tables for the product kernel ----
struct CPair { int l1,l2,cga; };
struct CTrip { int l1,l2,L,cga,l3,cgb; };
constexpr CPair cPR0[3]={{0,0,0},{1,1,44},{2,2,213}};
constexpr CPair cPR1[4]={{0,1,1},{1,0,35},{1,2,98},{2,1,168}};
constexpr CPair cPR2[4]={{0,2,10},{1,1,53},{2,0,143},{2,2,238}};
constexpr CTrip cTR0[11]={
  {0,0,0,0,0,0},{1,1,0,44,0,0},{2,2,0,213,0,0},
  {0,1,1,1,1,44},{1,0,1,35,1,44},{1,2,1,98,1,44},{2,1,1,168,1,44},
  {0,2,2,10,2,213},{1,1,2,53,2,213},{2,0,2,143,2,213},{2,2,2,238,2,213}};
constexpr CTrip cTR1[15]={
  {0,0,0,0,1,1},{1,1,0,44,1,1},{2,2,0,213,1,1},
  {0,1,1,1,0,35},{1,0,1,35,0,35},{1,2,1,98,0,35},{2,1,1,168,0,35},
  {0,1,1,1,2,98},{1,0,1,35,2,98},{1,2,1,98,2,98},{2,1,1,168,2,98},
  {0,2,2,10,1,168},{1,1,2,53,1,168},{2,0,2,143,1,168},{2,2,2,238,1,168}};
constexpr CTrip cTR2[15]={
  {0,0,0,0,2,10},{1,1,0,44,2,10},{2,2,0,213,2,10},
  {0,1,1,1,1,53},{1,0,1,35,1,53},{1,2,1,98,1,53},{2,1,1,168,1,53},
  {0,2,2,10,0,143},{1,1,2,53,0,143},{2,0,2,143,0,143},{2,2,2,238,0,143},
  {0,2,2,10,2,238},{1,1,2,53,2,238},{2,0,2,143,2,238},{2,2,2,238,2,238}};
constexpr CPair getPR(int lo,int p){ return lo==0?cPR0[p]:(lo==1?cPR1[p]:cPR2[p]); }
constexpr CTrip getTR(int lo,int p){ return lo==0?cTR0[p]:(lo==1?cTR1[p]:cTR2[p]); }
constexpr int cloff(int l){ return l==0?0:(l==1?1:4); }
constexpr int nPR(int lo){ return lo==0?3:4; }
constexpr int nTR(int lo){ return lo==0?11:15; }

template<int I> struct ic_t { static constexpr int v = I; };
template<int N, int I=0, typename F>
__device__ __forceinline__ void sfor(F&& f){
  if constexpr (I < N){ f(ic_t<I>{}); sfor<N, I+1>((F&&)f); }
}

__device__ __forceinline__ int loff_(int l){ return l==0?0:(l==1?1:4); }

__device__ __forceinline__ ushortt f2bf(float x){
  union { float f; unsigned int u; } a; a.f = x;
  unsigned int r = a.u + 0x7FFFu + ((a.u >> 16) & 1u);
  return (ushortt)(r >> 16);
}

__device__ __forceinline__ void gload_lds16(const void* g, void* lds){
  __builtin_amdgcn_global_load_lds((const __attribute__((address_space(1))) void*)g,
                                   (__attribute__((address_space(3))) void*)lds, 16, 0, 0);
}

// ---------------- device CG math ----------------
__device__ double d_fact(int n){ double f=1.0; for(int i=2;i<=n;i++) f*=(double)i; return f; }

__device__ double d_cg(int j1,int m1,int j2,int m2,int J,int M){
  if (M != m1+m2 || J < abs(j1-j2) || J > j1+j2) return 0.0;
  double pre = sqrt((2.0*J+1.0)*d_fact(J+j1-j2)*d_fact(J-j1+j2)*d_fact(j1+j2-J)/d_fact(j1+j2+J+1));
  pre *= sqrt(d_fact(J+M)*d_fact(J-M)*d_fact(j1-m1)*d_fact(j1+m1)*d_fact(j2-m2)*d_fact(j2+m2));
  double s=0.0;
  for(int k=0;k<=j1+j2-J;k++){
    int d0=k, d1=j1+j2-J-k, d2=j1-m1-k, d3=j2+m2-k, d4=J-j2+m1+k, d5=J-j1-m2+k;
    if (d0<0||d1<0||d2<0||d3<0||d4<0||d5<0) continue;
    double den = d_fact(d0)*d_fact(d1)*d_fact(d2)*d_fact(d3)*d_fact(d4)*d_fact(d5);
    s += ((k&1)?-1.0:1.0)/den;
  }
  return pre*s;
}

__device__ void d_u(int l, int i, int j, double* re, double* im){
  int m = i - l;
  *re=0.0; *im=0.0;
  const double s2 = 0.70710678118654752440;
  double par = (m & 1) ? -1.0 : 1.0;
  if (m < 0){
    if (j == m + l)  *im += s2;
    if (j == -m + l) *im += -par*s2;
  } else if (m == 0){
    if (j == l) *re = 1.0;
  } else {
    if (j == -m + l) *re += s2;
    if (j == m + l)  *re += par*s2;
  }
}

__global__ __launch_bounds__(128) void kcg1(double* tmp){
  int key = blockIdx.x;
  int l1=KEYL[key][0], l2=KEYL[key][1], l3=KEYL[key][2];
  int n1=2*l1+1, n2=2*l2+1, n3=2*l3+1;
  int nel=n1*n2*n3;
  int t=threadIdx.x;
  if (t>=nel) return;
  int a=t/(n2*n3), b=(t/n3)%n2, c=t%n3;
  double sre=0.0, sim=0.0;
  for (int mi=0;mi<n1;mi++)
    for (int ni=0;ni<n2;ni++){
      int m3 = (mi-l1)+(ni-l2);
      int oi = m3 + l3;
      if (oi<0 || oi>=n3) continue;
      double tc = d_cg(l1,mi-l1,l2,ni-l2,l3,m3);
      if (tc==0.0) continue;
      double r1,i1,r2,i2,r3,i3;
      d_u(l1,a,mi,&r1,&i1);
      d_u(l2,b,ni,&r2,&i2);
      d_u(l3,c,oi,&r3,&i3);
      double rr = r1*r2 - i1*i2;
      double ri = r1*i2 + i1*r2;
      double fr = rr*r3 + ri*i3;
      double fi = ri*r3 - rr*i3;
      sre += fr*tc; sim += fi*tc;
    }
  tmp[(size_t)(KEYOFF[key]+t)*2]   = sre;
  tmp[(size_t)(KEYOFF[key]+t)*2+1] = sim;
}

__global__ __launch_bounds__(64) void kcg2(const double* tmp, float* cgf){
  int key=threadIdx.x;
  if (key>=11) return;
  int off=KEYOFF[key], n=KEYOFF[key+1]-off;
  double sre=0.0, sim=0.0;
  for (int i=0;i<n;i++){ sre += fabs(tmp[(size_t)(off+i)*2]); sim += fabs(tmp[(size_t)(off+i)*2+1]); }
  bool takeRe = (sre >= sim);
  for (int i=0;i<n;i++) cgf[off+i] = (float)(takeRe ? tmp[(size_t)(off+i)*2] : tmp[(size_t)(off+i)*2+1]);
}

// ---------------- edge geometry ----------------
__global__ __launch_bounds__(256) void kgeom(const float* __restrict__ pos, const int* __restrict__ ei,
                                             float* __restrict__ shb, float* __restrict__ efb){
  int e = blockIdx.x*256+threadIdx.x;
  if (e>=NE) return;
  int s=ei[e], d=ei[NE+e];
  float vx=pos[s*3]-pos[d*3], vy=pos[s*3+1]-pos[d*3+1], vz=pos[s*3+2]-pos[d*3+2];
  float r = sqrtf(vx*vx+vy*vy+vz*vz);
  r = fmaxf(r, 1e-6f);
  float inv = 1.0f/r;
  float x=vx*inv, y=vy*inv, z=vz*inv;
  float* sh = shb + (size_t)e*9;
  const float s3=1.7320508075688772f, s15=3.872983346207417f, s5h=1.118033988749895f, s15h=1.9364916731037085f;
  sh[0]=1.0f;
  sh[1]=s3*y; sh[2]=s3*z; sh[3]=s3*x;
  sh[4]=s15*x*y; sh[5]=s15*y*z; sh[6]=s5h*(3.0f*z*z-1.0f); sh[7]=s15*x*z; sh[8]=s15h*(x*x-y*y);
  float u=r*0.1f;
  float cut=0.0f;
  if (u<1.0f){ float u2=u*u; float u5=u2*u2*u; cut = 1.0f - 21.0f*u5 + 35.0f*u5*u - 15.0f*u5*u2; }
  const float c0 = 0.4472135954999579f;
  const float PIF = 3.14159265358979323846f;
  float* ef = efb + (size_t)e*8;
  for (int j=0;j<8;j++)
    ef[j] = c0*sinf((float)(j+1)*PIF*r*0.1f)*inv*cut;
}

// ---------------- embedding ----------------
__global__ __launch_bounds__(256) void kembed(const float* __restrict__ x, const float* __restrict__ wemb,
                                              const float* __restrict__ bemb, float* __restrict__ h){
  int idx = blockIdx.x*256+threadIdx.x;
  if (idx>=NN*32) return;
  int n=idx>>5, k=idx&31;
  float a=bemb[k];
  for (int d=0;d<26;d++) a += x[n*26+d]*wemb[d*32+k];
  float* hp = h + (size_t)n*288 + k*9;
  hp[0]=a;
  #pragma unroll
  for (int c=1;c<9;c++) hp[c]=0.0f;
}

// ---------------- w2 transpose + bf16 cast ----------------
__global__ __launch_bounds__(256) void ktrans(const float* __restrict__ fc0_w2, const float* __restrict__ fcs_w2,
                                              ushortt* __restrict__ w2t0, ushortt* __restrict__ w2tH){
  int layer = blockIdx.z;
  int numel = (layer==0) ? 3072 : 11264;
  int c0 = blockIdx.x*32;
  if (c0 >= numel) return;
  const float* src = (layer==0) ? fc0_w2 : fcs_w2 + (size_t)(layer-1)*128*11264;
  ushortt* dst = (layer==0) ? w2t0 : w2tH + (size_t)(layer-1)*11264*128;
  int k0 = blockIdx.y*32;
  __shared__ float tile[32][33];
  int t = threadIdx.x;
  #pragma unroll
  for (int it=0; it<4; it++){
    int r = (t>>5) + it*8;
    tile[r][t&31] = src[(size_t)(k0+r)*numel + c0 + (t&31)];
  }
  __syncthreads();
  #pragma unroll
  for (int it=0; it<4; it++){
    int c = (t>>5) + it*8;
    int k = t&31;
    dst[(size_t)(c0+c)*128 + k0 + k] = f2bf(tile[k][c]);
  }
}

// ---------------- hidden MLP layer 1 -> bf16 (vectorized: 8 outputs/thread) ----------------
__global__ __launch_bounds__(256) void khid2(const float* __restrict__ efb, const float* __restrict__ w1,
                                             const float* __restrict__ b1, ushortt* __restrict__ hidbf){
  int idx = blockIdx.x*256+threadIdx.x;   // NE*16 total
  if (idx >= NE*16) return;
  int e = idx>>4, q = idx&15;
  int m0 = q*8;
  float efr[8];
  const float* ef = efb + (size_t)e*8;
  #pragma unroll
  for (int j=0;j<8;j++) efr[j]=ef[j];
  ushortt out8[8];
  #pragma unroll
  for (int mm=0;mm<8;mm++){
    int m = m0+mm;
    float a = b1[m];
    #pragma unroll
    for (int j=0;j<8;j++) a = fmaf(efr[j], w1[j*128+m], a);
    out8[mm] = f2bf(a>0.0f?a:0.0f);
  }
  *(short8*)(hidbf + (size_t)e*128 + m0) = *(const short8*)out8;
}

// ---------------- fused MFMA message kernel v5 (best measured) ----------------
// 256 threads / 4 waves; 64 edges/block; chunk = 64 cols double-buffered.
// A-fragments in regs; in-register t-contraction; output staged via LDS -> coalesced writes.
template<int NO>
__global__ __launch_bounds__(256, (NO==1?3:2)) void kmsg5(
    const float* __restrict__ hc, const float* __restrict__ shb,
    const ushortt* __restrict__ hidbf, const ushortt* __restrict__ w2t,
    const float* __restrict__ b2, const float* __restrict__ cg,
    const int* __restrict__ src, float* __restrict__ msgp, int plist){
  int p = (plist >> (blockIdx.y*8)) & 0xFF;
  int e0 = blockIdx.x*64;
  int li=PATHS[p].li, ls=PATHS[p].ls;
  int n1=2*li+1, ns=2*ls+1;
  int lioff=loff_(li), lsoff=loff_(ls);
  int cgoff=PATHS[p].cgoff;
  int comp=PATHS[p].comp;

  __shared__ __align__(16) ushortt sB[2][64*128];   // 32 KB
  __shared__ __align__(16) float   sT[NO*2048];     // NO*8 KB ([u*NO+o][64e]); reused as write staging
  __shared__ __align__(16) float   sB2[1024];       // 4 KB
  __shared__ int     sSRC[64];
  // overlay scratch inside sB[1]: dead before chunk-1 staging lands
  float* ov  = (float*)&sB[1][0];
  float* sCP = ov;          // 64*25 floats
  float* sSH = ov + 1600;   // 64*9 floats

  int t = threadIdx.x;
  int w = t>>6, l = t&63;

  // stage B chunk 0 (64 cols x 128 k)
  #pragma unroll
  for (int q=0;q<4;q++){
    int R0 = w*16 + q*4;
    int row = R0 + (l>>4);
    int ks = ((l&15)*8) ^ ((row&7)<<3);
    gload_lds16(w2t + (size_t)(p*1024 + row)*128 + ks, &sB[0][R0*128]);
  }
  // A-fragments direct to registers (wave w owns edge rows w*16..w*16+16)
  short8 av[4];
  {
    const ushortt* ap = hidbf + (size_t)(e0 + w*16 + (l&15))*128 + (l>>4)*8;
    #pragma unroll
    for (int kk=0;kk<4;kk++) av[kk] = *(const short8*)(ap + kk*32);
  }
  #pragma unroll
  for (int q=0;q<4;q++) sB2[t + q*256] = b2[p*1024 + t + q*256];
  if (t < 64) sSRC[t] = src[e0+t];
  for (int idx=t; idx<64*9; idx+=256) sSH[idx] = shb[(size_t)e0*9 + idx];
  __syncthreads();

  // cp[e][i][o] = sum_s CG[i,s,o]*sh[e][ls][s]
  for (int idx=t; idx<64*n1*NO; idx+=256){
    int e=idx/(n1*NO), r=idx%(n1*NO), i=r/NO, o=r%NO;
    float a=0.0f;
    for (int s=0;s<ns;s++) a += cg[cgoff + (i*ns+s)*NO+o]*sSH[e*9 + lsoff + s];
    sCP[e*25 + i*NO + o]=a;
  }
  __syncthreads();

  // t[u][o][e] = sum_i h[li][src[e]][u][i]*cp[e][i][o]
  for (int idx=t; idx<64*32; idx+=256){
    int e = idx&63, u = idx>>6;
    const float* hp = hc + (size_t)sSRC[e]*288 + u*9 + lioff;
    float hv[5];
    #pragma unroll
    for (int i=0;i<5;i++) hv[i] = hp[i];   // always in-bounds of node row
    #pragma unroll
    for (int o=0;o<NO;o++){
      float a=0.0f;
      #pragma unroll
      for (int i=0;i<5;i++) if (i<n1) a = fmaf(hv[i], sCP[e*25 + i*NO + o], a);
      sT[(u*NO+o)*64 + e] = a;
    }
  }
  __syncthreads();   // also drains chunk-0 staging

  float macc[4][2][NO];
  #pragma unroll
  for (int r=0;r<4;r++)
    #pragma unroll
    for (int vh=0;vh<2;vh++)
      #pragma unroll
      for (int o=0;o<NO;o++) macc[r][vh][o]=0.0f;

  int e_idx = w*16 + (l>>4)*4;

  for (int c=0;c<16;c++){
    int buf = c&1;
    if (c<15){
      #pragma unroll
      for (int q=0;q<4;q++){
        int R0 = w*16 + q*4;
        int row = R0 + (l>>4);
        int ks = ((l&15)*8) ^ ((row&7)<<3);
        gload_lds16(w2t + (size_t)(p*1024 + (c+1)*64 + row)*128 + ks, &sB[buf^1][R0*128]);
      }
    }
    // MFMA: C[64 x 64chunk]; wave w rows [w*16, w*16+16)
    f32x4 acc[4];
    #pragma unroll
    for (int fn=0;fn<4;fn++)
      #pragma unroll
      for (int r=0;r<4;r++) acc[fn][r]=0.0f;
    __builtin_amdgcn_s_setprio(1);
    #pragma unroll
    for (int kk=0; kk<4; kk++){
      #pragma unroll
      for (int fn=0; fn<4; fn++){
        int brow = fn*16 + (l&15);
        int kb = (kk*32 + (l>>4)*8) ^ ((brow&7)<<3);
        short8 bv = *(const short8*)&sB[buf][brow*128 + kb];
        acc[fn] = __builtin_amdgcn_mfma_f32_16x16x32_bf16(av[kk], bv, acc[fn], 0,0,0);
      }
    }
    __builtin_amdgcn_s_setprio(0);
    // in-register contraction: u-window = {2c, 2c+1}
    #pragma unroll
    for (int uu=0;uu<2;uu++){
      int ug = c*2 + uu;
      f32x4 tv[NO];
      #pragma unroll
      for (int o=0;o<NO;o++) tv[o] = *(const f32x4*)&sT[(ug*NO+o)*64 + e_idx];
      #pragma unroll
      for (int vh=0;vh<2;vh++){
        int fn = uu*2+vh;
        float b2v = sB2[c*64 + fn*16 + (l&15)];
        #pragma unroll
        for (int r=0;r<4;r++){
          float Cv = acc[fn][r] + b2v;
          #pragma unroll
          for (int o=0;o<NO;o++) macc[r][vh][o] = fmaf(Cv, tv[o][r], macc[r][vh][o]);
        }
      }
    }
    __syncthreads();
  }

  // ---- stage output into LDS (sT reused as sW), swizzled by e to spread banks ----
  float* sW = sT;
  #pragma unroll
  for (int r=0;r<4;r++){
    int e = e_idx + r;
    #pragma unroll
    for (int vh=0;vh<2;vh++){
      int v = vh*16 + (l&15);
      int g = v>>2;
      int addr = e*32 + (((g ^ (e&7)))<<2) + (v&3);
      #pragma unroll
      for (int o=0;o<NO;o++)
        sW[o*2048 + addr] = macc[r][vh][o];
    }
  }
  __syncthreads();
  // ---- stream out coalesced (full 128B lines) ----
  for (int j=t; j<NO*512; j+=256){
    int o = j>>9, q = j&511;
    int e = q>>3, gl = q&7;
    f32x4 vv = *(const f32x4*)&sW[o*2048 + e*32 + ((gl^(e&7))<<2)];
    *(f32x4*)(msgp + (size_t)(comp+o)*PLANE + (size_t)e0*32 + q*4) = vv;
  }
}

// ---------------- CSR build (once per forward) ----------------
__global__ __launch_bounds__(320) void kbuild(const int* __restrict__ dst, int* __restrict__ cnt, int* __restrict__ lst){
  int n = blockIdx.x;
  int t = threadIdx.x;
  __shared__ int s_dstl[NE];
  __shared__ int s_cnt[321];
  for (int idx=t; idx<NE; idx+=320) s_dstl[idx]=dst[idx];
  __syncthreads();
  const int per = NE/320;
  int start=t*per, end=start+per;
  int c=0;
  for (int e=start;e<end;++e) if (s_dstl[e]==n) c++;
  s_cnt[t+1]=c;
  if (t==0) s_cnt[0]=0;
  __syncthreads();
  if (t==0){ for (int i=1;i<=320;i++) s_cnt[i]+=s_cnt[i-1]; }
  __syncthreads();
  int pos = s_cnt[t];
  for (int e=start;e<end;++e) if (s_dstl[e]==n){ if (pos<CAP) lst[n*CAP+pos]=e; pos++; }
  if (t==0){ int M=s_cnt[320]; cnt[n]=(M<CAP)?M:CAP; }
}

// ---------------- gather via CSR (plane-major msg) ----------------
__global__ __launch_bounds__(320) void kgather2(const float* __restrict__ msgp, const int* __restrict__ cnt,
                                                const int* __restrict__ lst, float* __restrict__ mbuf, int full){
  int n = blockIdx.x;
  int t = threadIdx.x;
  if (t >= 288) return;
  int M = cnt[n];
  int jc = t>>5, k = t&31;
  float acc=0.0f;
  if (full){
    int pl0,pl1,pl2,pl3,np;
    if (jc==0){ pl0=0; pl1=12; pl2=29; pl3=0; np=3; }
    else if (jc<4){ int o=jc-1; pl0=1+o; pl1=9+o; pl2=18+o; pl3=26+o; np=4; }
    else { int o=jc-4; pl0=4+o; pl1=13+o; pl2=21+o; pl3=30+o; np=4; }
    for (int m=0;m<M;++m){
      int e = lst[n*CAP+m];
      int base = e*32 + k;
      float a = msgp[(size_t)pl0*PLANE + base] + msgp[(size_t)pl1*PLANE + base] + msgp[(size_t)pl2*PLANE + base];
      if (np==4) a += msgp[(size_t)pl3*PLANE + base];
      acc += a;
    }
  } else {
    for (int m=0;m<M;++m){
      int e = lst[n*CAP+m];
      acc += msgp[(size_t)jc*PLANE + e*32 + k];
    }
  }
  float norm = full ? (jc==0 ? 0.10206207261596577f : 0.08838834764831845f) : 0.17677669529663687f;
  mbuf[(size_t)n*288 + k*9 + jc] = acc*norm;
}

// ---------------- BN stats ----------------
__global__ __launch_bounds__(256) void kbn(const float* __restrict__ mbuf, float* __restrict__ stats){
  int k = blockIdx.x, t = threadIdx.x;
  float s0=0,sq0=0,sq1=0,sq2=0;
  for (int n=t;n<NN;n+=256){
    const float* mp = mbuf + (size_t)n*288 + k*9;
    float v0=mp[0]; s0+=v0; sq0+=v0*v0;
    float a=mp[1],b=mp[2],c=mp[3]; sq1+=a*a+b*b+c*c;
    float d=mp[4],e=mp[5],f=mp[6],g=mp[7],h=mp[8]; sq2+=d*d+e*e+f*f+g*g+h*h;
  }
  __shared__ float r[4][256];
  r[0][t]=s0; r[1][t]=sq0; r[2][t]=sq1; r[3][t]=sq2;
  __syncthreads();
  for (int s=128;s>0;s>>=1){
    if (t<s){ r[0][t]+=r[0][t+s]; r[1][t]+=r[1][t+s]; r[2][t]+=r[2][t+s]; r[3][t]+=r[3][t+s]; }
    __syncthreads();
  }
  if (t==0){
    float mu = r[0][0]/(float)NN;
    float var = r[1][0]/(float)NN - mu*mu;
    stats[k]      = mu;
    stats[32+k]   = rsqrtf(var + 1e-5f);
    stats[64+k]   = rsqrtf(r[2][0]/(float)NN + 1e-5f);
    stats[96+k]   = rsqrtf(r[3][0]/(float)NN + 1e-5f);
  }
}

// ---------------- tensor products, fully unrolled in registers ----------------
template<int CGA,int NA,int AO,int NB,int BO,int NO>
__device__ __forceinline__ void c2u(const float* __restrict__ cg, const float (&A)[9], const float (&B)[9], float (&out)[5]){
  #pragma unroll
  for (int o=0;o<NO;o++) out[o]=0.0f;
  #pragma unroll
  for (int i=0;i<NA;i++){
    #pragma unroll
    for (int j=0;j<NB;j++){
      float ab=A[AO+i]*B[BO+j];
      #pragma unroll
      for (int o=0;o<NO;o++) out[o]=fmaf(ab, cg[CGA+(i*NB+j)*NO+o], out[o]);
    }
  }
}
template<int CGA,int NA,int NB,int BO,int NO>
__device__ __forceinline__ void c2u5(const float* __restrict__ cg, const float (&Bb)[5], const float (&A)[9], float (&out)[5]){
  #pragma unroll
  for (int o=0;o<NO;o++) out[o]=0.0f;
  #pragma unroll
  for (int i=0;i<NA;i++){
    #pragma unroll
    for (int j=0;j<NB;j++){
      float ab=Bb[i]*A[BO+j];
      #pragma unroll
      for (int o=0;o<NO;o++) out[o]=fmaf(ab, cg[CGA+(i*NB+j)*NO+o], out[o]);
    }
  }
}

template<int LO>
__device__ __forceinline__ void do_lo(const float* __restrict__ cg, const float (&A)[9], float (&L)[9],
                                      const float* __restrict__ w1, const float* __restrict__ w2,
                                      const float* __restrict__ w3, int k){
  constexpr int NO=2*LO+1, AO=cloff(LO);
  float acc[5];
  float wc = w1[LO*32+k];
  #pragma unroll
  for (int o=0;o<NO;o++) acc[o]=wc*A[AO+o];
  sfor<nPR(LO)>([&](auto pc){
    constexpr int p = decltype(pc)::v;
    constexpr CPair P = getPR(LO,p);
    float tt[5];
    c2u<P.cga, 2*P.l1+1, cloff(P.l1), 2*P.l2+1, cloff(P.l2), NO>(cg, A, A, tt);
    float w = w2[(LO*4+p)*32+k];
    #pragma unroll
    for (int o=0;o<NO;o++) acc[o]=fmaf(w, tt[o], acc[o]);
  });
  sfor<nTR(LO)>([&](auto pc){
    constexpr int p = decltype(pc)::v;
    constexpr CTrip T = getTR(LO,p);
    constexpr int NL=2*T.L+1;
    float bb[5];
    c2u<T.cga, 2*T.l1+1, cloff(T.l1), 2*T.l2+1, cloff(T.l2), NL>(cg, A, A, bb);
    float tt[5];
    c2u5<T.cgb, NL, 2*T.l3+1, cloff(T.l3), NO>(cg, bb, A, tt);
    float w = w3[(LO*15+p)*32+k];
    #pragma unroll
    for (int o=0;o<NO;o++) acc[o]=fmaf(w, tt[o], acc[o]);
  });
  #pragma unroll
  for (int o=0;o<NO;o++) L[AO+o]=acc[o];
}

template<int LAST>
__global__ __launch_bounds__(256) void kprod3(const float* __restrict__ mbuf, const float* __restrict__ stats,
    const float* __restrict__ hc, float* __restrict__ hn,
    const float* __restrict__ bnw, const float* __restrict__ bnb,
    const float* __restrict__ w1, const float* __restrict__ w2, const float* __restrict__ w3,
    const float* __restrict__ plin, const float* __restrict__ cg, float* __restrict__ nodeout){
  int t = threadIdx.x;
  int nl = t>>5, k = t&31;
  int n = blockIdx.x*8 + nl;
  __shared__ float sL[8][32][9];
  float A[9], L[9];
  #pragma unroll
  for (int j=0;j<9;j++) L[j]=0.0f;
  const float* mp = mbuf + (size_t)n*288 + k*9;
  {
    float a0 = (mp[0]-stats[k])*stats[32+k]*bnw[k] + bnb[k];
    float f1 = stats[64+k]*bnw[32+k];
    float f2 = stats[96+k]*bnw[64+k];
    A[0]=a0;
    A[1]=mp[1]*f1; A[2]=mp[2]*f1; A[3]=mp[3]*f1;
    #pragma unroll
    for (int c=0;c<5;c++) A[4+c]=mp[4+c]*f2;
  }
  do_lo<0>(cg, A, L, w1, w2, w3, k);
  if constexpr (!LAST){
    do_lo<1>(cg, A, L, w1, w2, w3, k);
    do_lo<2>(cg, A, L, w1, w2, w3, k);
  }
  #pragma unroll
  for (int j=0;j<9;j++) sL[nl][k][j]=L[j];
  __syncthreads();

  if constexpr (!LAST){
    for (int idx=t; idx<8*288; idx+=256){
      int n2 = idx/288;
      int r  = idx%288;
      int jc = r>>5, v = r&31;
      int lo = (jc==0)?0:((jc<4)?1:2);
      float y=0.0f;
      const float* pl = plin + lo*1024 + v;
      for (int kk=0;kk<32;kk++)
        y = fmaf(sL[n2][kk][jc], pl[kk*32], y);
      int ng = blockIdx.x*8 + n2;
      y += hc[(size_t)ng*288 + v*9 + jc];
      hn[(size_t)ng*288 + v*9 + jc] = y;
    }
  } else {
    int n2 = t>>5, v = t&31;
    float y=0.0f;
    const float* pl = plin + v;
    for (int kk=0;kk<32;kk++)
      y = fmaf(sL[n2][kk][0], pl[kk*32], y);
    nodeout[(size_t)(blockIdx.x*8+n2)*32 + v] = y;
  }
}

// ---------------- graph segment sum (two-stage deterministic) ----------------
__global__ __launch_bounds__(256) void kgraphA(const float* __restrict__ nodeout, const int* __restrict__ batch,
                                               float* __restrict__ partial){
  int b = blockIdx.x;          // 125 blocks x 8 nodes
  int t = threadIdx.x;
  __shared__ float sv[8][32];
  __shared__ int   sg[8];
  int nl = t>>5, k = t&31;
  int n = b*8 + nl;
  sv[nl][k] = nodeout[(size_t)n*32 + k];
  if (k==0) sg[nl] = batch[n];
  __syncthreads();
  if (t < 128){
    int g = t>>5, kk = t&31;
    float acc=0.0f;
    #pragma unroll
    for (int j=0;j<8;j++) if (sg[j]==g) acc += sv[j][kk];
    partial[((size_t)b*4 + g)*32 + kk] = acc;
  }
}

__global__ __launch_bounds__(128) void kgraphB(const float* __restrict__ partial, float* __restrict__ gout){
  int t = threadIdx.x;
  int g = t>>5, k = t&31;
  float acc=0.0f;
  for (int b=0;b<125;b++) acc += partial[((size_t)b*4 + g)*32 + k];
  gout[g*32 + k] = acc;
}

// ---------------- launch ----------------
extern "C" void kernel_launch(void* const* d_in, const int* in_sizes, int n_in,
                              void* d_out, int out_size, void* d_ws, size_t ws_size,
                              hipStream_t stream) {
  const float* x      = (const float*)d_in[0];
  const float* pos    = (const float*)d_in[1];
  const int*   ei     = (const int*)d_in[2];
  const int*   batch  = (const int*)d_in[3];
  const float* w_emb  = (const float*)d_in[4];
  const float* b_emb  = (const float*)d_in[5];
  const float* fc0_w1 = (const float*)d_in[6];
  const float* fc0_b1 = (const float*)d_in[7];
  const float* fc0_w2 = (const float*)d_in[8];
  const float* fc0_b2 = (const float*)d_in[9];
  const float* fcs_w1 = (const float*)d_in[10];
  const float* fcs_b1 = (const float*)d_in[11];
  const float* fcs_w2 = (const float*)d_in[12];
  const float* fcs_b2 = (const float*)d_in[13];
  const float* bn_w   = (const float*)d_in[14];
  const float* bn_b   = (const float*)d_in[15];
  const float* pw1    = (const float*)d_in[16];
  const float* pw2    = (const float*)d_in[17];
  const float* pw3    = (const float*)d_in[18];
  const float* plin   = (const float*)d_in[19];

  double* cgtmp = (double*)d_ws;
  float*  F     = (float*)d_ws;
  float*  cgf   = F + 1456;
  float*  shb   = F + 1824;
  float*  efb   = F + 73824;
  float*  hA    = F + 137824;
  float*  hB    = F + 425824;
  float*  mbuf  = F + 713824;
  float*  stats = F + 1001824;
  float*  msgb  = F + 1001952;
  ushortt* hidbf = (ushortt*)(F + 9961952);
  ushortt* w2t0  = (ushortt*)(F + 10473952);
  ushortt* w2tH  = (ushortt*)(F + 10670560);
  int* csr_cnt = (int*)(F + 12833248);
  int* csr_lst = csr_cnt + 1024;
  float* partial = F + 12900000;   // 16000 floats

  float* nodeout = (float*)d_out;
  float* gout    = (float*)d_out + NN*32;

  kcg1<<<11,128,0,stream>>>(cgtmp);
  kcg2<<<1,64,0,stream>>>(cgtmp, cgf);
  kgeom<<<(NE+255)/256,256,0,stream>>>(pos, ei, shb, efb);
  kembed<<<(NN*32+255)/256,256,0,stream>>>(x, w_emb, b_emb, hA);
  ktrans<<<dim3(352,4,4),256,0,stream>>>(fc0_w2, fcs_w2, w2t0, w2tH);
  kbuild<<<NN,320,0,stream>>>(ei+NE, csr_cnt, csr_lst);

  float* hc = hA;
  float* hn = hB;
  for (int i=0;i<4;i++){
    const float *w1,*b1,*b2; const ushortt* w2t; int full;
    if (i==0){ w1=fc0_w1; b1=fc0_b1; w2t=w2t0; b2=fc0_b2; full=0; }
    else {
      int j=i-1;
      w1=fcs_w1 + (size_t)j*1024;
      b1=fcs_b1 + (size_t)j*128;
      w2t=w2tH + (size_t)j*11264*128;
      b2=fcs_b2 + (size_t)j*11264;
      full=1;
    }
    khid2<<<(NE*16+255)/256,256,0,stream>>>(efb, w1, b1, hidbf);
    if (full){
      kmsg5<1><<<dim3(125,3),256,0,stream>>>(hc, shb, hidbf, w2t, b2, cgf, ei, msgb, 0 | (4<<8) | (9<<16));
      kmsg5<3><<<dim3(125,4),256,0,stream>>>(hc, shb, hidbf, w2t, b2, cgf, ei, msgb, 1 | (3<<8) | (6<<16) | (8<<24));
      kmsg5<5><<<dim3(125,4),256,0,stream>>>(hc, shb, hidbf, w2t, b2, cgf, ei, msgb, 2 | (5<<8) | (7<<16) | (10<<24));
    } else {
      kmsg5<1><<<dim3(125,1),256,0,stream>>>(hc, shb, hidbf, w2t, b2, cgf, ei, msgb, 0);
      kmsg5<3><<<dim3(125,1),256,0,stream>>>(hc, shb, hidbf, w2t, b2, cgf, ei, msgb, 1);
      kmsg5<5><<<dim3(125,1),256,0,stream>>>(hc, shb, hidbf, w2t, b2, cgf, ei, msgb, 2);
    }
    kgather2<<<NN,320,0,stream>>>(msgb, csr_cnt, csr_lst, mbuf, full);
    kbn<<<32,256,0,stream>>>(mbuf, stats);
    int last = (i==3);
    const float* bw = bn_w + (size_t)i*96;
    const float* bb = bn_b + (size_t)i*32;
    const float* p1 = pw1 + (size_t)i*96;
    const float* p2 = pw2 + (size_t)i*384;
    const float* p3 = pw3 + (size_t)i*1440;
    const float* pl = plin + (size_t)i*3072;
    if (!last)
      kprod3<0><<<NN/8,256,0,stream>>>(mbuf, stats, hc, hn, bw, bb, p1, p2, p3, pl, cgf, nodeout);
    else
      kprod3<1><<<NN/8,256,0,stream>>>(mbuf, stats, hc, hn, bw, bb, p1, p2, p3, pl, cgf, nodeout);
    float* tmp=hc; hc=hn; hn=tmp;
  }
  kgraphA<<<125,256,0,stream>>>(nodeout, batch, partial);
  kgraphB<<<1,128,0,stream>>>(partial, gout);
}

// Round 16
// 581.202 us; speedup vs baseline: 1.6767x; 1.0063x over previous
//
#include <hip/hip_runtime.h>
#include <hip/hip_bf16.h>
#include <math.h>

#define NE 8000
#define NN 1000
#define CAP 64
#define PLANE 256000   // 8000*32

typedef unsigned short ushortt;
typedef __attribute__((ext_vector_type(8))) short short8;
typedef __attribute__((ext_vector_type(4))) float f32x4;

// ---------------- CG tables metadata ----------------
__device__ const int KEYL[11][3] = {{0,0,0},{0,1,1},{0,2,2},{1,0,1},{1,1,0},{1,1,2},{1,2,1},{2,0,2},{2,1,1},{2,2,0},{2,2,2}};
__device__ const int KEYOFF[12] = {0,1,10,35,44,53,98,143,168,213,238,363};

struct PathT { int li, ls, lo, cgoff, comp; };
__device__ const PathT PATHS[11] = {
 {0,0,0,  0, 0},{0,1,1,  1, 1},{0,2,2, 10, 4},{1,0,1, 35, 9},{1,1,0, 44,12},{1,1,2, 53,13},
 {1,2,1, 98,18},{2,0,2,143,21},{2,1,1,168,26},{2,2,0,213,29},{2,2,2,238,30}};

// ---- compile-time tables for the product kernel ----
struct CPair { int l1,l2,cga; };
struct CTrip { int l1,l2,L,cga,l3,cgb; };
constexpr CPair cPR0[3]={{0,0,0},{1,1,44},{2,2,213}};
constexpr CPair cPR1[4]={{0,1,1},{1,0,35},{1,2,98},{2,1,168}};
constexpr CPair cPR2[4]={{0,2,10},{1,1,53},{2,0,143},{2,2,238}};
constexpr CTrip cTR0[11]={
  {0,0,0,0,0,0},{1,1,0,44,0,0},{2,2,0,213,0,0},
  {0,1,1,1,1,44},{1,0,1,35,1,44},{1,2,1,98,1,44},{2,1,1,168,1,44},
  {0,2,2,10,2,213},{1,1,2,53,2,213},{2,0,2,143,2,213},{2,2,2,238,2,213}};
constexpr CTrip cTR1[15]={
  {0,0,0,0,1,1},{1,1,0,44,1,1},{2,2,0,213,1,1},
  {0,1,1,1,0,35},{1,0,1,35,0,35},{1,2,1,98,0,35},{2,1,1,168,0,35},
  {0,1,1,1,2,98},{1,0,1,35,2,98},{1,2,1,98,2,98},{2,1,1,168,2,98},
  {0,2,2,10,1,168},{1,1,2,53,1,168},{2,0,2,143,1,168},{2,2,2,238,1,168}};
constexpr CTrip cTR2[15]={
  {0,0,0,0,2,10},{1,1,0,44,2,10},{2,2,0,213,2,10},
  {0,1,1,1,1,53},{1,0,1,35,1,53},{1,2,1,98,1,53},{2,1,1,168,1,53},
  {0,2,2,10,0,143},{1,1,2,53,0,143},{2,0,2,143,0,143},{2,2,2,238,0,143},
  {0,2,2,10,2,238},{1,1,2,53,2,238},{2,0,2,143,2,238},{2,2,2,238,2,238}};
constexpr CPair getPR(int lo,int p){ return lo==0?cPR0[p]:(lo==1?cPR1[p]:cPR2[p]); }
constexpr CTrip getTR(int lo,int p){ return lo==0?cTR0[p]:(lo==1?cTR1[p]:cTR2[p]); }
constexpr int cloff(int l){ return l==0?0:(l==1?1:4); }
constexpr int nPR(int lo){ return lo==0?3:4; }
constexpr int nTR(int lo){ return lo==0?11:15; }

template<int I> struct ic_t { static constexpr int v = I; };
template<int N, int I=0, typename F>
__device__ __forceinline__ void sfor(F&& f){
  if constexpr (I < N){ f(ic_t<I>{}); sfor<N, I+1>((F&&)f); }
}

__device__ __forceinline__ int loff_(int l){ return l==0?0:(l==1?1:4); }

__device__ __forceinline__ ushortt f2bf(float x){
  union { float f; unsigned int u; } a; a.f = x;
  unsigned int r = a.u + 0x7FFFu + ((a.u >> 16) & 1u);
  return (ushortt)(r >> 16);
}

__device__ __forceinline__ void gload_lds16(const void* g, void* lds){
  __builtin_amdgcn_global_load_lds((const __attribute__((address_space(1))) void*)g,
                                   (__attribute__((address_space(3))) void*)lds, 16, 0, 0);
}

// ---------------- device CG math ----------------
__device__ double d_fact(int n){ double f=1.0; for(int i=2;i<=n;i++) f*=(double)i; return f; }

__device__ double d_cg(int j1,int m1,int j2,int m2,int J,int M){
  if (M != m1+m2 || J < abs(j1-j2) || J > j1+j2) return 0.0;
  double pre = sqrt((2.0*J+1.0)*d_fact(J+j1-j2)*d_fact(J-j1+j2)*d_fact(j1+j2-J)/d_fact(j1+j2+J+1));
  pre *= sqrt(d_fact(J+M)*d_fact(J-M)*d_fact(j1-m1)*d_fact(j1+m1)*d_fact(j2-m2)*d_fact(j2+m2));
  double s=0.0;
  for(int k=0;k<=j1+j2-J;k++){
    int d0=k, d1=j1+j2-J-k, d2=j1-m1-k, d3=j2+m2-k, d4=J-j2+m1+k, d5=J-j1-m2+k;
    if (d0<0||d1<0||d2<0||d3<0||d4<0||d5<0) continue;
    double den = d_fact(d0)*d_fact(d1)*d_fact(d2)*d_fact(d3)*d_fact(d4)*d_fact(d5);
    s += ((k&1)?-1.0:1.0)/den;
  }
  return pre*s;
}

__device__ void d_u(int l, int i, int j, double* re, double* im){
  int m = i - l;
  *re=0.0; *im=0.0;
  const double s2 = 0.70710678118654752440;
  double par = (m & 1) ? -1.0 : 1.0;
  if (m < 0){
    if (j == m + l)  *im += s2;
    if (j == -m + l) *im += -par*s2;
  } else if (m == 0){
    if (j == l) *re = 1.0;
  } else {
    if (j == -m + l) *re += s2;
    if (j == m + l)  *re += par*s2;
  }
}

__global__ __launch_bounds__(128) void kcg1(double* tmp){
  int key = blockIdx.x;
  int l1=KEYL[key][0], l2=KEYL[key][1], l3=KEYL[key][2];
  int n1=2*l1+1, n2=2*l2+1, n3=2*l3+1;
  int nel=n1*n2*n3;
  int t=threadIdx.x;
  if (t>=nel) return;
  int a=t/(n2*n3), b=(t/n3)%n2, c=t%n3;
  double sre=0.0, sim=0.0;
  for (int mi=0;mi<n1;mi++)
    for (int ni=0;ni<n2;ni++){
      int m3 = (mi-l1)+(ni-l2);
      int oi = m3 + l3;
      if (oi<0 || oi>=n3) continue;
      double tc = d_cg(l1,mi-l1,l2,ni-l2,l3,m3);
      if (tc==0.0) continue;
      double r1,i1,r2,i2,r3,i3;
      d_u(l1,a,mi,&r1,&i1);
      d_u(l2,b,ni,&r2,&i2);
      d_u(l3,c,oi,&r3,&i3);
      double rr = r1*r2 - i1*i2;
      double ri = r1*i2 + i1*r2;
      double fr = rr*r3 + ri*i3;
      double fi = ri*r3 - rr*i3;
      sre += fr*tc; sim += fi*tc;
    }
  tmp[(size_t)(KEYOFF[key]+t)*2]   = sre;
  tmp[(size_t)(KEYOFF[key]+t)*2+1] = sim;
}

__global__ __launch_bounds__(64) void kcg2(const double* tmp, float* cgf){
  int key=threadIdx.x;
  if (key>=11) return;
  int off=KEYOFF[key], n=KEYOFF[key+1]-off;
  double sre=0.0, sim=0.0;
  for (int i=0;i<n;i++){ sre += fabs(tmp[(size_t)(off+i)*2]); sim += fabs(tmp[(size_t)(off+i)*2+1]); }
  bool takeRe = (sre >= sim);
  for (int i=0;i<n;i++) cgf[off+i] = (float)(takeRe ? tmp[(size_t)(off+i)*2] : tmp[(size_t)(off+i)*2+1]);
}

// ---------------- edge geometry ----------------
__global__ __launch_bounds__(256) void kgeom(const float* __restrict__ pos, const int* __restrict__ ei,
                                             float* __restrict__ shb, float* __restrict__ efb){
  int e = blockIdx.x*256+threadIdx.x;
  if (e>=NE) return;
  int s=ei[e], d=ei[NE+e];
  float vx=pos[s*3]-pos[d*3], vy=pos[s*3+1]-pos[d*3+1], vz=pos[s*3+2]-pos[d*3+2];
  float r = sqrtf(vx*vx+vy*vy+vz*vz);
  r = fmaxf(r, 1e-6f);
  float inv = 1.0f/r;
  float x=vx*inv, y=vy*inv, z=vz*inv;
  float* sh = shb + (size_t)e*9;
  const float s3=1.7320508075688772f, s15=3.872983346207417f, s5h=1.118033988749895f, s15h=1.9364916731037085f;
  sh[0]=1.0f;
  sh[1]=s3*y; sh[2]=s3*z; sh[3]=s3*x;
  sh[4]=s15*x*y; sh[5]=s15*y*z; sh[6]=s5h*(3.0f*z*z-1.0f); sh[7]=s15*x*z; sh[8]=s15h*(x*x-y*y);
  float u=r*0.1f;
  float cut=0.0f;
  if (u<1.0f){ float u2=u*u; float u5=u2*u2*u; cut = 1.0f - 21.0f*u5 + 35.0f*u5*u - 15.0f*u5*u2; }
  const float c0 = 0.4472135954999579f;
  const float PIF = 3.14159265358979323846f;
  float* ef = efb + (size_t)e*8;
  for (int j=0;j<8;j++)
    ef[j] = c0*sinf((float)(j+1)*PIF*r*0.1f)*inv*cut;
}

// ---------------- embedding ----------------
__global__ __launch_bounds__(256) void kembed(const float* __restrict__ x, const float* __restrict__ wemb,
                                              const float* __restrict__ bemb, float* __restrict__ h){
  int idx = blockIdx.x*256+threadIdx.x;
  if (idx>=NN*32) return;
  int n=idx>>5, k=idx&31;
  float a=bemb[k];
  for (int d=0;d<26;d++) a += x[n*26+d]*wemb[d*32+k];
  float* hp = h + (size_t)n*288 + k*9;
  hp[0]=a;
  #pragma unroll
  for (int c=1;c<9;c++) hp[c]=0.0f;
}

// ---------------- w2 transpose + bf16 cast ----------------
__global__ __launch_bounds__(256) void ktrans(const float* __restrict__ fc0_w2, const float* __restrict__ fcs_w2,
                                              ushortt* __restrict__ w2t0, ushortt* __restrict__ w2tH){
  int layer = blockIdx.z;
  int numel = (layer==0) ? 3072 : 11264;
  int c0 = blockIdx.x*32;
  if (c0 >= numel) return;
  const float* src = (layer==0) ? fc0_w2 : fcs_w2 + (size_t)(layer-1)*128*11264;
  ushortt* dst = (layer==0) ? w2t0 : w2tH + (size_t)(layer-1)*11264*128;
  int k0 = blockIdx.y*32;
  __shared__ float tile[32][33];
  int t = threadIdx.x;
  #pragma unroll
  for (int it=0; it<4; it++){
    int r = (t>>5) + it*8;
    tile[r][t&31] = src[(size_t)(k0+r)*numel + c0 + (t&31)];
  }
  __syncthreads();
  #pragma unroll
  for (int it=0; it<4; it++){
    int c = (t>>5) + it*8;
    int k = t&31;
    dst[(size_t)(c0+c)*128 + k0 + k] = f2bf(tile[k][c]);
  }
}

// ---------------- hidden MLP layer 1 -> bf16 (vectorized: 8 outputs/thread) ----------------
__global__ __launch_bounds__(256) void khid2(const float* __restrict__ efb, const float* __restrict__ w1,
                                             const float* __restrict__ b1, ushortt* __restrict__ hidbf){
  int idx = blockIdx.x*256+threadIdx.x;   // NE*16 total
  if (idx >= NE*16) return;
  int e = idx>>4, q = idx&15;
  int m0 = q*8;
  float efr[8];
  const float* ef = efb + (size_t)e*8;
  #pragma unroll
  for (int j=0;j<8;j++) efr[j]=ef[j];
  ushortt out8[8];
  #pragma unroll
  for (int mm=0;mm<8;mm++){
    int m = m0+mm;
    float a = b1[m];
    #pragma unroll
    for (int j=0;j<8;j++) a = fmaf(efr[j], w1[j*128+m], a);
    out8[mm] = f2bf(a>0.0f?a:0.0f);
  }
  *(short8*)(hidbf + (size_t)e*128 + m0) = *(const short8*)out8;
}

// ---------------- fused MFMA message kernel v5 (best measured) ----------------
template<int NO>
__global__ __launch_bounds__(256, (NO==1?3:2)) void kmsg5(
    const float* __restrict__ hc, const float* __restrict__ shb,
    const ushortt* __restrict__ hidbf, const ushortt* __restrict__ w2t,
    const float* __restrict__ b2, const float* __restrict__ cg,
    const int* __restrict__ src, float* __restrict__ msgp, int plist){
  int p = (plist >> (blockIdx.y*8)) & 0xFF;
  int e0 = blockIdx.x*64;
  int li=PATHS[p].li, ls=PATHS[p].ls;
  int n1=2*li+1, ns=2*ls+1;
  int lioff=loff_(li), lsoff=loff_(ls);
  int cgoff=PATHS[p].cgoff;
  int comp=PATHS[p].comp;

  __shared__ __align__(16) ushortt sB[2][64*128];   // 32 KB
  __shared__ __align__(16) float   sT[NO*2048];     // NO*8 KB ([u*NO+o][64e]); reused as write staging
  __shared__ __align__(16) float   sB2[1024];       // 4 KB
  __shared__ int     sSRC[64];
  // overlay scratch inside sB[1]: dead before chunk-1 staging lands
  float* ov  = (float*)&sB[1][0];
  float* sCP = ov;          // 64*25 floats
  float* sSH = ov + 1600;   // 64*9 floats

  int t = threadIdx.x;
  int w = t>>6, l = t&63;

  // stage B chunk 0 (64 cols x 128 k)
  #pragma unroll
  for (int q=0;q<4;q++){
    int R0 = w*16 + q*4;
    int row = R0 + (l>>4);
    int ks = ((l&15)*8) ^ ((row&7)<<3);
    gload_lds16(w2t + (size_t)(p*1024 + row)*128 + ks, &sB[0][R0*128]);
  }
  // A-fragments direct to registers (wave w owns edge rows w*16..w*16+16)
  short8 av[4];
  {
    const ushortt* ap = hidbf + (size_t)(e0 + w*16 + (l&15))*128 + (l>>4)*8;
    #pragma unroll
    for (int kk=0;kk<4;kk++) av[kk] = *(const short8*)(ap + kk*32);
  }
  #pragma unroll
  for (int q=0;q<4;q++) sB2[t + q*256] = b2[p*1024 + t + q*256];
  if (t < 64) sSRC[t] = src[e0+t];
  for (int idx=t; idx<64*9; idx+=256) sSH[idx] = shb[(size_t)e0*9 + idx];
  __syncthreads();

  // cp[e][i][o] = sum_s CG[i,s,o]*sh[e][ls][s]
  for (int idx=t; idx<64*n1*NO; idx+=256){
    int e=idx/(n1*NO), r=idx%(n1*NO), i=r/NO, o=r%NO;
    float a=0.0f;
    for (int s=0;s<ns;s++) a += cg[cgoff + (i*ns+s)*NO+o]*sSH[e*9 + lsoff + s];
    sCP[e*25 + i*NO + o]=a;
  }
  __syncthreads();

  // t[u][o][e] = sum_i h[li][src[e]][u][i]*cp[e][i][o]
  for (int idx=t; idx<64*32; idx+=256){
    int e = idx&63, u = idx>>6;
    const float* hp = hc + (size_t)sSRC[e]*288 + u*9 + lioff;
    float hv[5];
    #pragma unroll
    for (int i=0;i<5;i++) hv[i] = hp[i];   // always in-bounds of node row
    #pragma unroll
    for (int o=0;o<NO;o++){
      float a=0.0f;
      #pragma unroll
      for (int i=0;i<5;i++) if (i<n1) a = fmaf(hv[i], sCP[e*25 + i*NO + o], a);
      sT[(u*NO+o)*64 + e] = a;
    }
  }
  __syncthreads();   // also drains chunk-0 staging

  float macc[4][2][NO];
  #pragma unroll
  for (int r=0;r<4;r++)
    #pragma unroll
    for (int vh=0;vh<2;vh++)
      #pragma unroll
      for (int o=0;o<NO;o++) macc[r][vh][o]=0.0f;

  int e_idx = w*16 + (l>>4)*4;

  for (int c=0;c<16;c++){
    int buf = c&1;
    if (c<15){
      #pragma unroll
      for (int q=0;q<4;q++){
        int R0 = w*16 + q*4;
        int row = R0 + (l>>4);
        int ks = ((l&15)*8) ^ ((row&7)<<3);
        gload_lds16(w2t + (size_t)(p*1024 + (c+1)*64 + row)*128 + ks, &sB[buf^1][R0*128]);
      }
    }
    // MFMA: C[64 x 64chunk]; wave w rows [w*16, w*16+16)
    f32x4 acc[4];
    #pragma unroll
    for (int fn=0;fn<4;fn++)
      #pragma unroll
      for (int r=0;r<4;r++) acc[fn][r]=0.0f;
    __builtin_amdgcn_s_setprio(1);
    #pragma unroll
    for (int kk=0; kk<4; kk++){
      #pragma unroll
      for (int fn=0; fn<4; fn++){
        int brow = fn*16 + (l&15);
        int kb = (kk*32 + (l>>4)*8) ^ ((brow&7)<<3);
        short8 bv = *(const short8*)&sB[buf][brow*128 + kb];
        acc[fn] = __builtin_amdgcn_mfma_f32_16x16x32_bf16(av[kk], bv, acc[fn], 0,0,0);
      }
    }
    __builtin_amdgcn_s_setprio(0);
    // in-register contraction: u-window = {2c, 2c+1}
    #pragma unroll
    for (int uu=0;uu<2;uu++){
      int ug = c*2 + uu;
      f32x4 tv[NO];
      #pragma unroll
      for (int o=0;o<NO;o++) tv[o] = *(const f32x4*)&sT[(ug*NO+o)*64 + e_idx];
      #pragma unroll
      for (int vh=0;vh<2;vh++){
        int fn = uu*2+vh;
        float b2v = sB2[c*64 + fn*16 + (l&15)];
        #pragma unroll
        for (int r=0;r<4;r++){
          float Cv = acc[fn][r] + b2v;
          #pragma unroll
          for (int o=0;o<NO;o++) macc[r][vh][o] = fmaf(Cv, tv[o][r], macc[r][vh][o]);
        }
      }
    }
    __syncthreads();
  }

  // ---- stage output into LDS (sT reused as sW), swizzled by e to spread banks ----
  float* sW = sT;
  #pragma unroll
  for (int r=0;r<4;r++){
    int e = e_idx + r;
    #pragma unroll
    for (int vh=0;vh<2;vh++){
      int v = vh*16 + (l&15);
      int g = v>>2;
      int addr = e*32 + (((g ^ (e&7)))<<2) + (v&3);
      #pragma unroll
      for (int o=0;o<NO;o++)
        sW[o*2048 + addr] = macc[r][vh][o];
    }
  }
  __syncthreads();
  // ---- stream out coalesced (full 128B lines) ----
  for (int j=t; j<NO*512; j+=256){
    int o = j>>9, q = j&511;
    int e = q>>3, gl = q&7;
    f32x4 vv = *(const f32x4*)&sW[o*2048 + e*32 + ((gl^(e&7))<<2)];
    *(f32x4*)(msgp + (size_t)(comp+o)*PLANE + (size_t)e0*32 + q*4) = vv;
  }
}

// ---------------- CSR build (once per forward) ----------------
__global__ __launch_bounds__(320) void kbuild(const int* __restrict__ dst, int* __restrict__ cnt, int* __restrict__ lst){
  int n = blockIdx.x;
  int t = threadIdx.x;
  __shared__ int s_dstl[NE];
  __shared__ int s_cnt[321];
  for (int idx=t; idx<NE; idx+=320) s_dstl[idx]=dst[idx];
  __syncthreads();
  const int per = NE/320;
  int start=t*per, end=start+per;
  int c=0;
  for (int e=start;e<end;++e) if (s_dstl[e]==n) c++;
  s_cnt[t+1]=c;
  if (t==0) s_cnt[0]=0;
  __syncthreads();
  if (t==0){ for (int i=1;i<=320;i++) s_cnt[i]+=s_cnt[i-1]; }
  __syncthreads();
  int pos = s_cnt[t];
  for (int e=start;e<end;++e) if (s_dstl[e]==n){ if (pos<CAP) lst[n*CAP+pos]=e; pos++; }
  if (t==0){ int M=s_cnt[320]; cnt[n]=(M<CAP)?M:CAP; }
}

// ---------------- gather via CSR (plane-major msg) ----------------
__global__ __launch_bounds__(320) void kgather2(const float* __restrict__ msgp, const int* __restrict__ cnt,
                                                const int* __restrict__ lst, float* __restrict__ mbuf, int full){
  int n = blockIdx.x;
  int t = threadIdx.x;
  if (t >= 288) return;
  int M = cnt[n];
  int jc = t>>5, k = t&31;
  float acc=0.0f;
  if (full){
    int pl0,pl1,pl2,pl3,np;
    if (jc==0){ pl0=0; pl1=12; pl2=29; pl3=0; np=3; }
    else if (jc<4){ int o=jc-1; pl0=1+o; pl1=9+o; pl2=18+o; pl3=26+o; np=4; }
    else { int o=jc-4; pl0=4+o; pl1=13+o; pl2=21+o; pl3=30+o; np=4; }
    for (int m=0;m<M;++m){
      int e = lst[n*CAP+m];
      int base = e*32 + k;
      float a = msgp[(size_t)pl0*PLANE + base] + msgp[(size_t)pl1*PLANE + base] + msgp[(size_t)pl2*PLANE + base];
      if (np==4) a += msgp[(size_t)pl3*PLANE + base];
      acc += a;
    }
  } else {
    for (int m=0;m<M;++m){
      int e = lst[n*CAP+m];
      acc += msgp[(size_t)jc*PLANE + e*32 + k];
    }
  }
  float norm = full ? (jc==0 ? 0.10206207261596577f : 0.08838834764831845f) : 0.17677669529663687f;
  mbuf[(size_t)n*288 + k*9 + jc] = acc*norm;
}

// ---------------- BN stats ----------------
__global__ __launch_bounds__(256) void kbn(const float* __restrict__ mbuf, float* __restrict__ stats){
  int k = blockIdx.x, t = threadIdx.x;
  float s0=0,sq0=0,sq1=0,sq2=0;
  for (int n=t;n<NN;n+=256){
    const float* mp = mbuf + (size_t)n*288 + k*9;
    float v0=mp[0]; s0+=v0; sq0+=v0*v0;
    float a=mp[1],b=mp[2],c=mp[3]; sq1+=a*a+b*b+c*c;
    float d=mp[4],e=mp[5],f=mp[6],g=mp[7],h=mp[8]; sq2+=d*d+e*e+f*f+g*g+h*h;
  }
  __shared__ float r[4][256];
  r[0][t]=s0; r[1][t]=sq0; r[2][t]=sq1; r[3][t]=sq2;
  __syncthreads();
  for (int s=128;s>0;s>>=1){
    if (t<s){ r[0][t]+=r[0][t+s]; r[1][t]+=r[1][t+s]; r[2][t]+=r[2][t+s]; r[3][t]+=r[3][t+s]; }
    __syncthreads();
  }
  if (t==0){
    float mu = r[0][0]/(float)NN;
    float var = r[1][0]/(float)NN - mu*mu;
    stats[k]      = mu;
    stats[32+k]   = rsqrtf(var + 1e-5f);
    stats[64+k]   = rsqrtf(r[2][0]/(float)NN + 1e-5f);
    stats[96+k]   = rsqrtf(r[3][0]/(float)NN + 1e-5f);
  }
}

// ---------------- tensor products, fully unrolled in registers ----------------
template<int CGA,int NA,int AO,int NB,int BO,int NO>
__device__ __forceinline__ void c2u(const float* __restrict__ cg, const float (&A)[9], const float (&B)[9], float (&out)[5]){
  #pragma unroll
  for (int o=0;o<NO;o++) out[o]=0.0f;
  #pragma unroll
  for (int i=0;i<NA;i++){
    #pragma unroll
    for (int j=0;j<NB;j++){
      float ab=A[AO+i]*B[BO+j];
      #pragma unroll
      for (int o=0;o<NO;o++) out[o]=fmaf(ab, cg[CGA+(i*NB+j)*NO+o], out[o]);
    }
  }
}
template<int CGA,int NA,int NB,int BO,int NO>
__device__ __forceinline__ void c2u5(const float* __restrict__ cg, const float (&Bb)[5], const float (&A)[9], float (&out)[5]){
  #pragma unroll
  for (int o=0;o<NO;o++) out[o]=0.0f;
  #pragma unroll
  for (int i=0;i<NA;i++){
    #pragma unroll
    for (int j=0;j<NB;j++){
      float ab=Bb[i]*A[BO+j];
      #pragma unroll
      for (int o=0;o<NO;o++) out[o]=fmaf(ab, cg[CGA+(i*NB+j)*NO+o], out[o]);
    }
  }
}

template<int LO>
__device__ __forceinline__ void do_lo(const float* __restrict__ cg, const float (&A)[9], float (&L)[9],
                                      const float* __restrict__ w1, const float* __restrict__ w2,
                                      const float* __restrict__ w3, int k){
  constexpr int NO=2*LO+1, AO=cloff(LO);
  float acc[5];
  float wc = w1[LO*32+k];
  #pragma unroll
  for (int o=0;o<NO;o++) acc[o]=wc*A[AO+o];
  sfor<nPR(LO)>([&](auto pc){
    constexpr int p = decltype(pc)::v;
    constexpr CPair P = getPR(LO,p);
    float tt[5];
    c2u<P.cga, 2*P.l1+1, cloff(P.l1), 2*P.l2+1, cloff(P.l2), NO>(cg, A, A, tt);
    float w = w2[(LO*4+p)*32+k];
    #pragma unroll
    for (int o=0;o<NO;o++) acc[o]=fmaf(w, tt[o], acc[o]);
  });
  sfor<nTR(LO)>([&](auto pc){
    constexpr int p = decltype(pc)::v;
    constexpr CTrip T = getTR(LO,p);
    constexpr int NL=2*T.L+1;
    float bb[5];
    c2u<T.cga, 2*T.l1+1, cloff(T.l1), 2*T.l2+1, cloff(T.l2), NL>(cg, A, A, bb);
    float tt[5];
    c2u5<T.cgb, NL, 2*T.l3+1, cloff(T.l3), NO>(cg, bb, A, tt);
    float w = w3[(LO*15+p)*32+k];
    #pragma unroll
    for (int o=0;o<NO;o++) acc[o]=fmaf(w, tt[o], acc[o]);
  });
  #pragma unroll
  for (int o=0;o<NO;o++) L[AO+o]=acc[o];
}

// ---- kprod4: 2 nodes per 64-thread block (1 wave), grid 500 — full-CU coverage ----
template<int LAST>
__global__ __launch_bounds__(64) void kprod4(const float* __restrict__ mbuf, const float* __restrict__ stats,
    const float* __restrict__ hc, float* __restrict__ hn,
    const float* __restrict__ bnw, const float* __restrict__ bnb,
    const float* __restrict__ w1, const float* __restrict__ w2, const float* __restrict__ w3,
    const float* __restrict__ plin, const float* __restrict__ cg, float* __restrict__ nodeout){
  int t = threadIdx.x;
  int nl = t>>5, k = t&31;
  int n = blockIdx.x*2 + nl;
  __shared__ float sL[2][32][9];
  float A[9], L[9];
  #pragma unroll
  for (int j=0;j<9;j++) L[j]=0.0f;
  const float* mp = mbuf + (size_t)n*288 + k*9;
  {
    float a0 = (mp[0]-stats[k])*stats[32+k]*bnw[k] + bnb[k];
    float f1 = stats[64+k]*bnw[32+k];
    float f2 = stats[96+k]*bnw[64+k];
    A[0]=a0;
    A[1]=mp[1]*f1; A[2]=mp[2]*f1; A[3]=mp[3]*f1;
    #pragma unroll
    for (int c=0;c<5;c++) A[4+c]=mp[4+c]*f2;
  }
  do_lo<0>(cg, A, L, w1, w2, w3, k);
  if constexpr (!LAST){
    do_lo<1>(cg, A, L, w1, w2, w3, k);
    do_lo<2>(cg, A, L, w1, w2, w3, k);
  }
  #pragma unroll
  for (int j=0;j<9;j++) sL[nl][k][j]=L[j];
  __syncthreads();

  if constexpr (!LAST){
    for (int idx=t; idx<2*288; idx+=64){
      int n2 = idx/288;
      int r  = idx%288;
      int jc = r>>5, v = r&31;
      int lo = (jc==0)?0:((jc<4)?1:2);
      float y=0.0f;
      const float* pl = plin + lo*1024 + v;
      for (int kk=0;kk<32;kk++)
        y = fmaf(sL[n2][kk][jc], pl[kk*32], y);
      int ng = blockIdx.x*2 + n2;
      y += hc[(size_t)ng*288 + v*9 + jc];
      hn[(size_t)ng*288 + v*9 + jc] = y;
    }
  } else {
    int n2 = t>>5, v = t&31;
    float y=0.0f;
    const float* pl = plin + v;
    for (int kk=0;kk<32;kk++)
      y = fmaf(sL[n2][kk][0], pl[kk*32], y);
    nodeout[(size_t)(blockIdx.x*2+n2)*32 + v] = y;
  }
}

// ---------------- graph segment sum (two-stage deterministic) ----------------
__global__ __launch_bounds__(256) void kgraphA(const float* __restrict__ nodeout, const int* __restrict__ batch,
                                               float* __restrict__ partial){
  int b = blockIdx.x;          // 125 blocks x 8 nodes
  int t = threadIdx.x;
  __shared__ float sv[8][32];
  __shared__ int   sg[8];
  int nl = t>>5, k = t&31;
  int n = b*8 + nl;
  sv[nl][k] = nodeout[(size_t)n*32 + k];
  if (k==0) sg[nl] = batch[n];
  __syncthreads();
  if (t < 128){
    int g = t>>5, kk = t&31;
    float acc=0.0f;
    #pragma unroll
    for (int j=0;j<8;j++) if (sg[j]==g) acc += sv[j][kk];
    partial[((size_t)b*4 + g)*32 + kk] = acc;
  }
}

__global__ __launch_bounds__(128) void kgraphB(const float* __restrict__ partial, float* __restrict__ gout){
  int t = threadIdx.x;
  int g = t>>5, k = t&31;
  float acc=0.0f;
  for (int b=0;b<125;b++) acc += partial[((size_t)b*4 + g)*32 + k];
  gout[g*32 + k] = acc;
}

// ---------------- launch ----------------
extern "C" void kernel_launch(void* const* d_in, const int* in_sizes, int n_in,
                              void* d_out, int out_size, void* d_ws, size_t ws_size,
                              hipStream_t stream) {
  const float* x      = (const float*)d_in[0];
  const float* pos    = (const float*)d_in[1];
  const int*   ei     = (const int*)d_in[2];
  const int*   batch  = (const int*)d_in[3];
  const float* w_emb  = (const float*)d_in[4];
  const float* b_emb  = (const float*)d_in[5];
  const float* fc0_w1 = (const float*)d_in[6];
  const float* fc0_b1 = (const float*)d_in[7];
  const float* fc0_w2 = (const float*)d_in[8];
  const float* fc0_b2 = (const float*)d_in[9];
  const float* fcs_w1 = (const float*)d_in[10];
  const float* fcs_b1 = (const float*)d_in[11];
  const float* fcs_w2 = (const float*)d_in[12];
  const float* fcs_b2 = (const float*)d_in[13];
  const float* bn_w   = (const float*)d_in[14];
  const float* bn_b   = (const float*)d_in[15];
  const float* pw1    = (const float*)d_in[16];
  const float* pw2    = (const float*)d_in[17];
  const float* pw3    = (const float*)d_in[18];
  const float* plin   = (const float*)d_in[19];

  double* cgtmp = (double*)d_ws;
  float*  F     = (float*)d_ws;
  float*  cgf   = F + 1456;
  float*  shb   = F + 1824;
  float*  efb   = F + 73824;
  float*  hA    = F + 137824;
  float*  hB    = F + 425824;
  float*  mbuf  = F + 713824;
  float*  stats = F + 1001824;
  float*  msgb  = F + 1001952;
  ushortt* hidbf = (ushortt*)(F + 9961952);
  ushortt* w2t0  = (ushortt*)(F + 10473952);
  ushortt* w2tH  = (ushortt*)(F + 10670560);
  int* csr_cnt = (int*)(F + 12833248);
  int* csr_lst = csr_cnt + 1024;
  float* partial = F + 12900000;   // 16000 floats

  float* nodeout = (float*)d_out;
  float* gout    = (float*)d_out + NN*32;

  kcg1<<<11,128,0,stream>>>(cgtmp);
  kcg2<<<1,64,0,stream>>>(cgtmp, cgf);
  kgeom<<<(NE+255)/256,256,0,stream>>>(pos, ei, shb, efb);
  kembed<<<(NN*32+255)/256,256,0,stream>>>(x, w_emb, b_emb, hA);
  ktrans<<<dim3(352,4,4),256,0,stream>>>(fc0_w2, fcs_w2, w2t0, w2tH);
  kbuild<<<NN,320,0,stream>>>(ei+NE, csr_cnt, csr_lst);

  float* hc = hA;
  float* hn = hB;
  for (int i=0;i<4;i++){
    const float *w1,*b1,*b2; const ushortt* w2t; int full;
    if (i==0){ w1=fc0_w1; b1=fc0_b1; w2t=w2t0; b2=fc0_b2; full=0; }
    else {
      int j=i-1;
      w1=fcs_w1 + (size_t)j*1024;
      b1=fcs_b1 + (size_t)j*128;
      w2t=w2tH + (size_t)j*11264*128;
      b2=fcs_b2 + (size_t)j*11264;
      full=1;
    }
    khid2<<<(NE*16+255)/256,256,0,stream>>>(efb, w1, b1, hidbf);
    if (full){
      kmsg5<1><<<dim3(125,3),256,0,stream>>>(hc, shb, hidbf, w2t, b2, cgf, ei, msgb, 0 | (4<<8) | (9<<16));
      kmsg5<3><<<dim3(125,4),256,0,stream>>>(hc, shb, hidbf, w2t, b2, cgf, ei, msgb, 1 | (3<<8) | (6<<16) | (8<<24));
      kmsg5<5><<<dim3(125,4),256,0,stream>>>(hc, shb, hidbf, w2t, b2, cgf, ei, msgb, 2 | (5<<8) | (7<<16) | (10<<24));
    } else {
      kmsg5<1><<<dim3(125,1),256,0,stream>>>(hc, shb, hidbf, w2t, b2, cgf, ei, msgb, 0);
      kmsg5<3><<<dim3(125,1),256,0,stream>>>(hc, shb, hidbf, w2t, b2, cgf, ei, msgb, 1);
      kmsg5<5><<<dim3(125,1),256,0,stream>>>(hc, shb, hidbf, w2t, b2, cgf, ei, msgb, 2);
    }
    kgather2<<<NN,320,0,stream>>>(msgb, csr_cnt, csr_lst, mbuf, full);
    kbn<<<32,256,0,stream>>>(mbuf, stats);
    int last = (i==3);
    const float* bw = bn_w + (size_t)i*96;
    const float* bb = bn_b + (size_t)i*32;
    const float* p1 = pw1 + (size_t)i*96;
    const float* p2 = pw2 + (size_t)i*384;
    const float* p3 = pw3 + (size_t)i*1440;
    const float* pl = plin + (size_t)i*3072;
    if (!last)
      kprod4<0><<<NN/2,64,0,stream>>>(mbuf, stats, hc, hn, bw, bb, p1, p2, p3, pl, cgf, nodeout);
    else
      kprod4<1><<<NN/2,64,0,stream>>>(mbuf, stats, hc, hn, bw, bb, p1, p2, p3, pl, cgf, nodeout);
    float* tmp=hc; hc=hn; hn=tmp;
  }
  kgraphA<<<125,256,0,stream>>>(nodeout, batch, partial);
  kgraphB<<<1,128,0,stream>>>(partial, gout);
}